// Round 16
// baseline (217.451 us; speedup 1.0000x reference)
//
#include <hip/hip_runtime.h>
#include <hip/hip_fp16.h>

// SDConv on MI355X.
// Reference: out = sum_k spmm(L_k, X) @ W_k + bias  (complex).
// Structure: apply W AFTER the spmm (k-expansion lives in the L domain), so the
// gather table is just X: 25.6 MB fp16 -> L2/L3-resident.
//   1. xh_zero_kernel: Xh[node][ch] = half2(Xr, Xi); zero coarse-bucket counters.
//   2. Hierarchical CSR build (random-64B-line writeback amplification measured
//      R9/R10/R12; occupancy lessons R13 partA + R15 partB): chist -> cscan(+Wpack)
//      -> partA (burst writes of 32 B pre-swizzled records, 1024-thr) ->
//      partB (per-bucket fine sort, L2-local, 1024-thr; emits rowst).
//   3. row6_kernel (FUSED row pass + output GEMM): block = 16 rows; 4 waves x 4 rows
//      each, 6-slot payload pipeline / 4 gathers in flight, 6 dot2/edge; Y in LDS
//      (400 B row pitch); barrier; each wave MFMAs its 16-col quadrant and
//      NT-stores out + bias.

constexpr int N_NODES = 100000;
constexpr int E_EDGES = 1600000;
constexpr int CH = 64;
constexpr int NP = 100096;          // N padded to multiple of 256
constexpr int NBUCK = NP / 256;     // 391 coarse buckets (256 rows each)
constexpr int CHUNK_A = 4096;       // edges per partition block
constexpr int NBLK_A = (E_EDGES + CHUNK_A - 1) / CHUNK_A;   // 391

typedef unsigned u32x4 __attribute__((ext_vector_type(4)));
typedef _Float16 h2f __attribute__((ext_vector_type(2)));
typedef _Float16 h8f __attribute__((ext_vector_type(8)));
typedef float f32x4 __attribute__((ext_vector_type(4)));

// f32 += dot(half2, half2) with f32 accumulation (v_dot2_f32_f16).
__device__ __forceinline__ float fdot2h(unsigned a, unsigned b, float c) {
#if __has_builtin(__builtin_amdgcn_fdot2)
    return __builtin_amdgcn_fdot2(__builtin_bit_cast(h2f, a),
                                  __builtin_bit_cast(h2f, b), c, false);
#else
    float2 af = __half22float2(__builtin_bit_cast(__half2, a));
    float2 bf = __half22float2(__builtin_bit_cast(__half2, b));
    return c + af.x * bf.x + af.y * bf.y;
#endif
}

__device__ __forceinline__ unsigned pack2(float a, float b) {
    return __builtin_bit_cast(unsigned, __floats2half2_rn(a, b));
}

__global__ __launch_bounds__(256) void init_out_kernel(const float* __restrict__ bias,
                                                       float* __restrict__ out) {
    int i = blockIdx.x * 256 + threadIdx.x;
    out[i] = bias[i & 63];
}

// ---------------- Phase 1: Xh = half2(Xr, Xi), [N][64]; zero bucket counters ----------------
__global__ __launch_bounds__(256) void xh_zero_kernel(const float* __restrict__ Xr,
                                                      const float* __restrict__ Xi,
                                                      unsigned* __restrict__ Xh,
                                                      int* __restrict__ bcnt) {
    int i = blockIdx.x * 256 + threadIdx.x;   // grid = N*64/4/256 = 6250 exact
    if (i < NBUCK) bcnt[i] = 0;
    const float4 r = ((const float4*)Xr)[i];
    const float4 m = ((const float4*)Xi)[i];
    uint4 u;
    u.x = pack2(r.x, m.x);
    u.y = pack2(r.y, m.y);
    u.z = pack2(r.z, m.z);
    u.w = pack2(r.w, m.w);
    ((uint4*)Xh)[i] = u;
}

// ---------------- Coarse bucket histogram (1024-thread blocks) ----------------
__global__ __launch_bounds__(1024) void chist_kernel(const int* __restrict__ rows,
                                                     int* __restrict__ bcnt) {
    __shared__ int lh[NBUCK];
    const int tid = threadIdx.x;
    for (int t = tid; t < NBUCK; t += 1024) lh[t] = 0;
    __syncthreads();
    const int base = blockIdx.x * CHUNK_A;
    for (int j = tid; j < CHUNK_A; j += 1024) {
        const int e = base + j;
        if (e < E_EDGES) atomicAdd(&lh[__builtin_nontemporal_load(rows + e) >> 8], 1);
    }
    __syncthreads();
    for (int t = tid; t < NBUCK; t += 1024)
        if (lh[t]) atomicAdd(&bcnt[t], lh[t]);
}

// ---------------- Scan of 391 bucket counts + W pack (single block) ----------------
// Bpack[(kc*4+nt)*64 + L] = 8 halves: W[kc*32 + (L>>4)*8 + j][nt*16 + (L&15)]
__global__ __launch_bounds__(512) void cscan_kernel(const int* __restrict__ bcnt,
                                                    int* __restrict__ cofs,
                                                    int* __restrict__ ccur,
                                                    const float* __restrict__ W,
                                                    h8f* __restrict__ Bpack) {
    __shared__ int s[512];
    const int t = threadIdx.x;
    int v = (t < NBUCK) ? bcnt[t] : 0;
    s[t] = v;
    __syncthreads();
    for (int off = 1; off < 512; off <<= 1) {
        int a = (t >= off) ? s[t - off] : 0;
        __syncthreads();
        s[t] += a;
        __syncthreads();
    }
    if (t < NBUCK) {
        cofs[t] = s[t] - v;
        ccur[t] = s[t] - v;
    }
    if (t == NBUCK - 1) cofs[NBUCK] = s[t];   // == E_EDGES

    // W -> MFMA B-fragment pack (independent of scan)
    for (int sidx = t; sidx < 24 * 64; sidx += 512) {
        const int L = sidx & 63;
        const int ntkc = sidx >> 6;
        const int nt = ntkc & 3;
        const int kc = ntkc >> 2;
        const int colb = nt * 16 + (L & 15);
        const int kbase = kc * 32 + ((L >> 4) << 3);
        h8f vv;
#pragma unroll
        for (int j = 0; j < 8; ++j) vv[j] = (_Float16)W[(kbase + j) * 64 + colb];
        Bpack[sidx] = vv;
    }
}

// ---------------- Phase A: coarse partition, burst writes of 32 B records ----------------
// record: {col, (lr0,-li0), (li0,lr0), (lr1,-li1)} {(li1,lr1), (lr2,-li2), (li2,lr2), row&255}
__global__ __launch_bounds__(1024) void partA_kernel(const int* __restrict__ rows,
                                                     const int* __restrict__ cols,
                                                     const float* __restrict__ Lr,
                                                     const float* __restrict__ Li,
                                                     int* __restrict__ ccur,
                                                     u32x4* __restrict__ temp) {
    __shared__ int lh[NBUCK];
    __shared__ int lcur[NBUCK];
    const int tid = threadIdx.x;
    for (int t = tid; t < NBUCK; t += 1024) lh[t] = 0;
    __syncthreads();
    const int base = blockIdx.x * CHUNK_A;
    for (int j = tid; j < CHUNK_A; j += 1024) {
        const int e = base + j;
        if (e < E_EDGES) atomicAdd(&lh[__builtin_nontemporal_load(rows + e) >> 8], 1);
    }
    __syncthreads();
    for (int t = tid; t < NBUCK; t += 1024) {
        const int c = lh[t];
        lcur[t] = c ? atomicAdd(&ccur[t], c) : 0;    // one global atomic per (block,bucket)
    }
    __syncthreads();
    for (int j = tid; j < CHUNK_A; j += 1024) {
        const int e = base + j;
        if (e >= E_EDGES) continue;
        const int r = __builtin_nontemporal_load(rows + e);
        const int pos = atomicAdd(&lcur[r >> 8], 1);
        const float lr0 = __builtin_nontemporal_load(Lr + e);
        const float li0 = __builtin_nontemporal_load(Li + e);
        const float lr1 = __builtin_nontemporal_load(Lr + E_EDGES + e);
        const float li1 = __builtin_nontemporal_load(Li + E_EDGES + e);
        const float lr2 = __builtin_nontemporal_load(Lr + 2 * E_EDGES + e);
        const float li2 = __builtin_nontemporal_load(Li + 2 * E_EDGES + e);
        u32x4 u0, u1;
        u0.x = (unsigned)__builtin_nontemporal_load(cols + e);
        u0.y = pack2(lr0, -li0);
        u0.z = pack2(li0, lr0);
        u0.w = pack2(lr1, -li1);
        u1.x = pack2(li1, lr1);
        u1.y = pack2(lr2, -li2);
        u1.z = pack2(li2, lr2);
        u1.w = (unsigned)(r & 255);
        temp[2 * (size_t)pos] = u0;        // burst-local: lines mostly covered
        temp[2 * (size_t)pos + 1] = u1;
    }
}

// ---------------- Phase B: per-bucket fine sort (L2-local), 1024 threads ----------------
__global__ __launch_bounds__(1024) void partB_kernel(const int* __restrict__ cofs,
                                                     const u32x4* __restrict__ temp,
                                                     u32x4* __restrict__ payload,
                                                     int* __restrict__ rowst) {
    const int b = blockIdx.x;                 // grid = NBUCK
    const int t = threadIdx.x;
    const int start = cofs[b];
    const int endp = cofs[b + 1];
    __shared__ int lh[256];
    __shared__ int s[256];
    if (t < 256) lh[t] = 0;
    __syncthreads();
    for (int i = start + t; i < endp; i += 1024) {
        u32x4 q1 = __builtin_nontemporal_load(temp + 2 * (size_t)i + 1);
        atomicAdd(&lh[q1.w], 1);
    }
    __syncthreads();
    int v = 0;
    if (t < 256) {
        v = lh[t];
        s[t] = v;
    }
    __syncthreads();
    for (int off = 1; off < 256; off <<= 1) {
        int a = (t >= off && t < 256) ? s[t - off] : 0;
        __syncthreads();
        if (t < 256) s[t] += a;
        __syncthreads();
    }
    if (t < 256) {
        const int excl = s[t] - v;
        rowst[b * 256 + t] = start + excl;
        lh[t] = excl;                          // becomes per-row cursor
    }
    if (b == NBUCK - 1 && t == 0) rowst[NBUCK * 256] = endp;   // guard
    __syncthreads();
    for (int i = start + t; i < endp; i += 1024) {
        u32x4 q0 = __builtin_nontemporal_load(temp + 2 * (size_t)i);
        u32x4 q1 = __builtin_nontemporal_load(temp + 2 * (size_t)i + 1);
        const int rl = (int)q1.w;
        q1.w = 0u;
        const int pos = start + atomicAdd(&lh[rl], 1);   // random within ~131 KB -> L2
        payload[2 * (size_t)pos] = q0;
        payload[2 * (size_t)pos + 1] = q1;
    }
}

// ---------------- FUSED main pass: 16 rows/block; edge phase + MFMA epilogue ----------------
__global__ __launch_bounds__(256) void row6_kernel(const int* __restrict__ rowst,
                                                   const u32x4* __restrict__ payload,
                                                   const unsigned* __restrict__ Xh,
                                                   const h8f* __restrict__ Bpack,
                                                   const float* __restrict__ bias,
                                                   float* __restrict__ out) {
    __shared__ __half sY[2][16][200];          // 400 B row pitch: 2-way LDS alias only
    const int w = (int)threadIdx.x >> 6;       // wave id = 4 rows / nt quadrant
    const int lane = threadIdx.x & 63;
    const int band = blockIdx.x * 16;          // grid = 6250 exact

    for (int q = 0; q < 4; ++q) {
        const int ri = w * 4 + q;
        const int r = __builtin_amdgcn_readfirstlane(band + ri);
        const int start = rowst[r];
        const int end = rowst[r + 1];
        const int n = end - start;

        float aR0 = 0.f, aI0 = 0.f, aR1 = 0.f, aI1 = 0.f, aR2 = 0.f, aI2 = 0.f;

        auto gx = [&](unsigned col) -> unsigned { return Xh[(size_t)col * 64 + lane]; };
        auto pld = [&](int p) -> u32x4 {
            return __builtin_nontemporal_load(payload + p);    // read-once stream
        };
        auto accum = [&](const u32x4& q0, const u32x4& q1, unsigned xv) {
            aR0 = fdot2h(q0.y, xv, aR0);
            aI0 = fdot2h(q0.z, xv, aI0);
            aR1 = fdot2h(q0.w, xv, aR1);
            aI1 = fdot2h(q1.x, xv, aI1);
            aR2 = fdot2h(q1.y, xv, aR2);
            aI2 = fdot2h(q1.z, xv, aI2);
        };

        if (n >= 8) {
            int p = start;
            u32x4 A0 = pld(2 * p), A1 = pld(2 * p + 1);
            u32x4 B0 = pld(2 * (p + 1)), B1 = pld(2 * (p + 1) + 1);
            u32x4 C0 = pld(2 * (p + 2)), C1 = pld(2 * (p + 2) + 1);
            u32x4 D0 = pld(2 * (p + 3)), D1 = pld(2 * (p + 3) + 1);
            u32x4 E0 = pld(2 * (p + 4)), E1 = pld(2 * (p + 4) + 1);
            u32x4 F0 = pld(2 * (p + 5)), F1 = pld(2 * (p + 5) + 1);
            unsigned xA = gx(A0.x), xB = gx(B0.x), xC = gx(C0.x), xD = gx(D0.x);

            for (; p + 7 < end; p += 2) {
                u32x4 G0 = pld(2 * (p + 6)), G1 = pld(2 * (p + 6) + 1);
                u32x4 H0 = pld(2 * (p + 7)), H1 = pld(2 * (p + 7) + 1);
                unsigned xE = gx(E0.x);
                unsigned xF = gx(F0.x);
                accum(A0, A1, xA);
                accum(B0, B1, xB);
                A0 = C0; A1 = C1; xA = xC;
                B0 = D0; B1 = D1; xB = xD;
                C0 = E0; C1 = E1; xC = xE;
                D0 = F0; D1 = F1; xD = xF;
                E0 = G0; E1 = G1;
                F0 = H0; F1 = H1;
            }
            accum(A0, A1, xA);
            accum(B0, B1, xB);
            accum(C0, C1, xC);
            accum(D0, D1, xD);
            unsigned xE = gx(E0.x);
            unsigned xF = gx(F0.x);
            accum(E0, E1, xE);
            accum(F0, F1, xF);
            if (p + 6 < end) {
                u32x4 G0 = pld(2 * (p + 6)), G1 = pld(2 * (p + 6) + 1);
                unsigned xG = gx(G0.x);
                accum(G0, G1, xG);
            }
        } else {
            for (int p = start; p < end; ++p) {
                u32x4 q0 = pld(2 * p), q1 = pld(2 * p + 1);
                unsigned xv = gx(q0.x);
                accum(q0, q1, xv);
            }
        }

        sY[0][ri][lane] = __float2half(aR0);
        sY[0][ri][64 + lane] = __float2half(aR1);
        sY[0][ri][128 + lane] = __float2half(aR2);
        sY[1][ri][lane] = __float2half(aI0);
        sY[1][ri][64 + lane] = __float2half(aI1);
        sY[1][ri][128 + lane] = __float2half(aI2);
    }
    __syncthreads();

    // MFMA epilogue: wave w = column quadrant nt = w.
    const int nt = w;
    const int m = lane & 15;
    const int ko = (lane >> 4) << 3;
    f32x4 accR = (f32x4){0.f, 0.f, 0.f, 0.f};
    f32x4 accI = (f32x4){0.f, 0.f, 0.f, 0.f};
#pragma unroll
    for (int kc = 0; kc < 6; ++kc) {
        h8f bf = Bpack[(kc * 4 + nt) * 64 + lane];                    // L3-hot, 16 B/lane
        h8f aR = *(const h8f*)&sY[0][m][kc * 32 + ko];
        h8f aI = *(const h8f*)&sY[1][m][kc * 32 + ko];
        accR = __builtin_amdgcn_mfma_f32_16x16x32_f16(aR, bf, accR, 0, 0, 0);
        accI = __builtin_amdgcn_mfma_f32_16x16x32_f16(aI, bf, accI, 0, 0, 0);
    }
    const int colw = lane & 15;
    const int rbase = (lane >> 4) << 2;
    const float b = bias[nt * 16 + colw];
#pragma unroll
    for (int rr = 0; rr < 4; ++rr) {
        const int row = band + rbase + rr;
        __builtin_nontemporal_store(accR[rr] + b,
                                    &out[(size_t)row * 64 + nt * 16 + colw]);
        __builtin_nontemporal_store(accI[rr] + b,
                                    &out[(size_t)(N_NODES + row) * 64 + nt * 16 + colw]);
    }
}

// ================= Fallback kernels (small-ws paths) =================
template <int NK>
__global__ __launch_bounds__(256) void xw_kernel(const float* __restrict__ Xr,
                                                 const float* __restrict__ Xi,
                                                 const float* __restrict__ W,
                                                 __half2* __restrict__ XWh) {
    __shared__ float sW[NK][64][64];
    __shared__ float4 sX4[2][32][16];
    const int tid = threadIdx.x;

    float4* swf = (float4*)&sW[0][0][0];
    const float4* gW = (const float4*)W;
    for (int i = tid; i < NK * 1024; i += 256) swf[i] = gW[i];

    const int rowbase = blockIdx.x * 32;
    float4* sxf = (float4*)sX4;
    const float4* gXr = (const float4*)(Xr + (size_t)rowbase * CH);
    const float4* gXi = (const float4*)(Xi + (size_t)rowbase * CH);
    for (int i = tid; i < 512; i += 256) {
        sxf[i] = gXr[i];
        sxf[512 + i] = gXi[i];
    }
    __syncthreads();

    const int col = tid & 63;
    const int rg = tid >> 6;

    float acc[8][2 * NK];
#pragma unroll
    for (int i = 0; i < 8; ++i)
#pragma unroll
        for (int c2 = 0; c2 < 2 * NK; ++c2) acc[i][c2] = 0.0f;

#pragma unroll 2
    for (int j4 = 0; j4 < 16; ++j4) {
        float w[NK][4];
#pragma unroll
        for (int k = 0; k < NK; ++k)
#pragma unroll
            for (int jj = 0; jj < 4; ++jj) w[k][jj] = sW[k][j4 * 4 + jj][col];
#pragma unroll
        for (int i = 0; i < 8; ++i) {
            float4 xr = sX4[0][rg * 8 + i][j4];
            float4 xi = sX4[1][rg * 8 + i][j4];
            const float xra[4] = {xr.x, xr.y, xr.z, xr.w};
            const float xia[4] = {xi.x, xi.y, xi.z, xi.w};
#pragma unroll
            for (int jj = 0; jj < 4; ++jj)
#pragma unroll
                for (int k = 0; k < NK; ++k) {
                    acc[i][2 * k] += xra[jj] * w[k][jj];
                    acc[i][2 * k + 1] += xia[jj] * w[k][jj];
                }
        }
    }

#pragma unroll
    for (int i = 0; i < 8; ++i) {
        __half2* dst = XWh + (size_t)(rowbase + rg * 8 + i) * (NK * 64);
#pragma unroll
        for (int k = 0; k < NK; ++k)
            dst[k * 64 + col] = __floats2half2_rn(acc[i][2 * k], acc[i][2 * k + 1]);
    }
}

template <int NK>
__global__ __launch_bounds__(256) void edge_kernel(const int* __restrict__ rows,
                                                   const int* __restrict__ cols,
                                                   const float* __restrict__ Lr,
                                                   const float* __restrict__ Li,
                                                   const __half2* __restrict__ XWh,
                                                   float* __restrict__ out) {
    const int gid = blockIdx.x * 256 + threadIdx.x;
    const int e = gid >> 6;
    const int lane = gid & 63;
    if (e >= E_EDGES) return;

    const int row = rows[e];
    const int colN = cols[e];
    const __half2* xw = XWh + (size_t)colN * (NK * 64);

    float rc = 0.0f, ic = 0.0f;
#pragma unroll
    for (int k = 0; k < NK; ++k) {
        const float lr = Lr[(size_t)k * E_EDGES + e];
        const float li = Li[(size_t)k * E_EDGES + e];
        float2 v = __half22float2(xw[k * 64 + lane]);
        rc += lr * v.x - li * v.y;
        ic += li * v.x + lr * v.y;
    }
    unsafeAtomicAdd(out + (size_t)row * 64 + lane, rc);
    unsafeAtomicAdd(out + ((size_t)N_NODES + row) * 64 + lane, ic);
}

extern "C" void kernel_launch(void* const* d_in, const int* in_sizes, int n_in,
                              void* d_out, int out_size, void* d_ws, size_t ws_size,
                              hipStream_t stream) {
    const float* Xr = (const float*)d_in[0];
    const float* Xi = (const float*)d_in[1];
    const int* ei = (const int*)d_in[2];
    const float* Lr = (const float*)d_in[3];
    const float* Li = (const float*)d_in[4];
    const float* W = (const float*)d_in[5];
    const float* bias = (const float*)d_in[6];
    float* out = (float*)d_out;

    const int* rows = ei;
    const int* cols = ei + E_EDGES;

    char* wsb = (char*)d_ws;
    const int edge_grid = (int)((size_t)E_EDGES * 64 / 256);      // 400000
    const int gemm_grid = N_NODES / 32;                           // 3125

    // Main-path ws layout
    unsigned* Xh = (unsigned*)wsb;                                //  25,600,000 B
    unsigned* payload = (unsigned*)(wsb + 25600000);              //  51,200,000 B (32 B/edge)
    u32x4* temp = (u32x4*)(wsb + 76800000);                       //  51,200,000 B
    int* rowst = (int*)(wsb + 128000000);                         //     404,480 B (NP+1 used)
    int* bcnt = (int*)(wsb + 128404480);                          //       1,600 B
    int* cofs = (int*)(wsb + 128406080);                          //       1,600 B
    int* ccur = (int*)(wsb + 128407680);                          //       1,600 B
    h8f* Bpack = (h8f*)(wsb + 128409280);                         //      24,576 B
    const size_t need_new = 128433856;

    if (ws_size >= need_new) {
        xh_zero_kernel<<<6250, 256, 0, stream>>>(Xr, Xi, Xh, bcnt);
        chist_kernel<<<NBLK_A, 1024, 0, stream>>>(rows, bcnt);
        cscan_kernel<<<1, 512, 0, stream>>>(bcnt, cofs, ccur, W, Bpack);
        partA_kernel<<<NBLK_A, 1024, 0, stream>>>(rows, cols, Lr, Li, ccur, temp);
        partB_kernel<<<NBUCK, 1024, 0, stream>>>(cofs, temp, (u32x4*)payload, rowst);
        row6_kernel<<<N_NODES / 16, 256, 0, stream>>>(rowst, (const u32x4*)payload, Xh,
                                                      Bpack, bias, out);
        return;
    }

    // Fallback ws layout (atomic edge scatter over XWh table)
    __half2* XWh = (__half2*)wsb;                                 //  76,800,000 B
    const size_t need_onepass = 76800000;

    if (ws_size >= need_onepass) {
        init_out_kernel<<<2 * N_NODES * CH / 256, 256, 0, stream>>>(bias, out);
        xw_kernel<3><<<gemm_grid, 256, 0, stream>>>(Xr, Xi, W, XWh);
        edge_kernel<3><<<edge_grid, 256, 0, stream>>>(rows, cols, Lr, Li, XWh, out);
    } else {
        init_out_kernel<<<2 * N_NODES * CH / 256, 256, 0, stream>>>(bias, out);
        for (int k = 0; k < 3; ++k) {
            xw_kernel<1><<<gemm_grid, 256, 0, stream>>>(Xr, Xi, W + (size_t)k * 4096, XWh);
            edge_kernel<1><<<edge_grid, 256, 0, stream>>>(rows, cols,
                                                          Lr + (size_t)k * E_EDGES,
                                                          Li + (size_t)k * E_EDGES, XWh, out);
        }
    }
}

// Round 17
// 178.516 us; speedup vs baseline: 1.2181x; 1.2181x over previous
//
#include <hip/hip_runtime.h>
#include <hip/hip_fp16.h>

// SDConv on MI355X.
// Reference: out = sum_k spmm(L_k, X) @ W_k + bias  (complex).
// Structure: apply W AFTER the spmm (k-expansion lives in the L domain), so the
// gather table is just X: 25.6 MB fp16 -> L2/L3-resident.
//   1. xh_zero_kernel: Xh[node][ch] = half2(Xr, Xi); zero coarse-bucket counters.
//   2. Hierarchical CSR build (random-64B-line writeback amplification R9/R10/R12;
//      occupancy R13/R15; NT-load lesson R16: NT loads hurt reused streams):
//      chist -> cscan(+Wpack) -> partA (LDS-staged radix partition with
//      bucket-sorted COALESCED copy-out) -> partB (per-bucket fine sort, L2-local,
//      1024-thr; emits rowst).
//   3. row6_kernel (FUSED row pass + output GEMM): block = 16 rows; 4 waves x 4 rows
//      each, 6-slot payload pipeline / 4 gathers in flight, 6 dot2/edge; Y in LDS
//      (400 B row pitch); barrier; MFMA per 16-col quadrant; NT-stores out + bias.

constexpr int N_NODES = 100000;
constexpr int E_EDGES = 1600000;
constexpr int CH = 64;
constexpr int NP = 100096;          // N padded to multiple of 256
constexpr int NBUCK = NP / 256;     // 391 coarse buckets (256 rows each)
constexpr int CHUNK_A = 2048;       // edges per partition block
constexpr int NBLK_A = (E_EDGES + CHUNK_A - 1) / CHUNK_A;   // 782

typedef unsigned u32x4 __attribute__((ext_vector_type(4)));
typedef _Float16 h2f __attribute__((ext_vector_type(2)));
typedef _Float16 h8f __attribute__((ext_vector_type(8)));
typedef float f32x4 __attribute__((ext_vector_type(4)));

// f32 += dot(half2, half2) with f32 accumulation (v_dot2_f32_f16).
__device__ __forceinline__ float fdot2h(unsigned a, unsigned b, float c) {
#if __has_builtin(__builtin_amdgcn_fdot2)
    return __builtin_amdgcn_fdot2(__builtin_bit_cast(h2f, a),
                                  __builtin_bit_cast(h2f, b), c, false);
#else
    float2 af = __half22float2(__builtin_bit_cast(__half2, a));
    float2 bf = __half22float2(__builtin_bit_cast(__half2, b));
    return c + af.x * bf.x + af.y * bf.y;
#endif
}

__device__ __forceinline__ unsigned pack2(float a, float b) {
    return __builtin_bit_cast(unsigned, __floats2half2_rn(a, b));
}

__global__ __launch_bounds__(256) void init_out_kernel(const float* __restrict__ bias,
                                                       float* __restrict__ out) {
    int i = blockIdx.x * 256 + threadIdx.x;
    out[i] = bias[i & 63];
}

// ---------------- Phase 1: Xh = half2(Xr, Xi), [N][64]; zero bucket counters ----------------
__global__ __launch_bounds__(256) void xh_zero_kernel(const float* __restrict__ Xr,
                                                      const float* __restrict__ Xi,
                                                      unsigned* __restrict__ Xh,
                                                      int* __restrict__ bcnt) {
    int i = blockIdx.x * 256 + threadIdx.x;   // grid = N*64/4/256 = 6250 exact
    if (i < NBUCK) bcnt[i] = 0;
    const float4 r = ((const float4*)Xr)[i];
    const float4 m = ((const float4*)Xi)[i];
    uint4 u;
    u.x = pack2(r.x, m.x);
    u.y = pack2(r.y, m.y);
    u.z = pack2(r.z, m.z);
    u.w = pack2(r.w, m.w);
    ((uint4*)Xh)[i] = u;
}

// ---------------- Coarse bucket histogram ----------------
__global__ __launch_bounds__(1024) void chist_kernel(const int* __restrict__ rows,
                                                     int* __restrict__ bcnt) {
    __shared__ int lh[NBUCK];
    const int tid = threadIdx.x;
    for (int t = tid; t < NBUCK; t += 1024) lh[t] = 0;
    __syncthreads();
    const int base = blockIdx.x * CHUNK_A;
    const int nedge = min(CHUNK_A, E_EDGES - base);
    for (int j = tid; j < nedge; j += 1024) atomicAdd(&lh[rows[base + j] >> 8], 1);
    __syncthreads();
    for (int t = tid; t < NBUCK; t += 1024)
        if (lh[t]) atomicAdd(&bcnt[t], lh[t]);
}

// ---------------- Scan of 391 bucket counts + W pack (single block) ----------------
// Bpack[(kc*4+nt)*64 + L] = 8 halves: W[kc*32 + (L>>4)*8 + j][nt*16 + (L&15)]
__global__ __launch_bounds__(512) void cscan_kernel(const int* __restrict__ bcnt,
                                                    int* __restrict__ cofs,
                                                    int* __restrict__ ccur,
                                                    const float* __restrict__ W,
                                                    h8f* __restrict__ Bpack) {
    __shared__ int s[512];
    const int t = threadIdx.x;
    int v = (t < NBUCK) ? bcnt[t] : 0;
    s[t] = v;
    __syncthreads();
    for (int off = 1; off < 512; off <<= 1) {
        int a = (t >= off) ? s[t - off] : 0;
        __syncthreads();
        s[t] += a;
        __syncthreads();
    }
    if (t < NBUCK) {
        cofs[t] = s[t] - v;
        ccur[t] = s[t] - v;
    }
    if (t == NBUCK - 1) cofs[NBUCK] = s[t];   // == E_EDGES

    // W -> MFMA B-fragment pack (independent of scan)
    for (int sidx = t; sidx < 24 * 64; sidx += 512) {
        const int L = sidx & 63;
        const int ntkc = sidx >> 6;
        const int nt = ntkc & 3;
        const int kc = ntkc >> 2;
        const int colb = nt * 16 + (L & 15);
        const int kbase = kc * 32 + ((L >> 4) << 3);
        h8f vv;
#pragma unroll
        for (int j = 0; j < 8; ++j) vv[j] = (_Float16)W[(kbase + j) * 64 + colb];
        Bpack[sidx] = vv;
    }
}

// ---------------- Phase A: LDS-staged radix partition, coalesced copy-out ----------------
// record: {col, (lr0,-li0), (li0,lr0), (lr1,-li1)} {(li1,lr1), (lr2,-li2), (li2,lr2), row&255}
__global__ __launch_bounds__(1024) void partA_kernel(const int* __restrict__ rows,
                                                     const int* __restrict__ cols,
                                                     const float* __restrict__ Lr,
                                                     const float* __restrict__ Li,
                                                     int* __restrict__ ccur,
                                                     u32x4* __restrict__ temp) {
    __shared__ u32x4 sRec[2 * CHUNK_A];   // 65,536 B, bucket-sorted records
    __shared__ int sDst[CHUNK_A];         //  8,192 B, global record index per record
    __shared__ int lh[NBUCK];
    __shared__ int lcur[NBUCK];
    __shared__ int gdel[NBUCK];           // global base - LDS base
    __shared__ int ss[512];
    const int tid = threadIdx.x;
    const int base = blockIdx.x * CHUNK_A;
    const int nedge = min(CHUNK_A, E_EDGES - base);

    for (int t = tid; t < NBUCK; t += 1024) lh[t] = 0;
    __syncthreads();
    for (int j = tid; j < nedge; j += 1024) atomicAdd(&lh[rows[base + j] >> 8], 1);
    __syncthreads();

    if (tid < 512) ss[tid] = (tid < NBUCK) ? lh[tid] : 0;
    __syncthreads();
    for (int off = 1; off < 512; off <<= 1) {
        int a = 0;
        if (tid < 512 && tid >= off) a = ss[tid - off];
        __syncthreads();
        if (tid < 512) ss[tid] += a;
        __syncthreads();
    }
    if (tid < NBUCK) {
        const int excl = ss[tid] - lh[tid];
        lcur[tid] = excl;
        const int gb = lh[tid] ? atomicAdd(&ccur[tid], lh[tid]) : 0;
        gdel[tid] = gb - excl;            // one global atomic per (block,bucket)
    }
    __syncthreads();

    for (int j = tid; j < nedge; j += 1024) {
        const int e = base + j;
        const int r = rows[e];
        const int bk = r >> 8;
        const int pos = atomicAdd(&lcur[bk], 1);
        const float lr0 = Lr[e], li0 = Li[e];
        const float lr1 = Lr[E_EDGES + e], li1 = Li[E_EDGES + e];
        const float lr2 = Lr[2 * E_EDGES + e], li2 = Li[2 * E_EDGES + e];
        u32x4 u0, u1;
        u0.x = (unsigned)cols[e];
        u0.y = pack2(lr0, -li0);
        u0.z = pack2(li0, lr0);
        u0.w = pack2(lr1, -li1);
        u1.x = pack2(li1, lr1);
        u1.y = pack2(lr2, -li2);
        u1.z = pack2(li2, lr2);
        u1.w = (unsigned)(r & 255);
        sRec[2 * pos] = u0;
        sRec[2 * pos + 1] = u1;
        sDst[pos] = gdel[bk] + pos;       // global record index
    }
    __syncthreads();

    // Coalesced copy-out: consecutive lanes -> consecutive chunks; bucket-sorted
    // LDS order makes global destinations piecewise-consecutive (~5-record runs).
    const int nchunk = 2 * nedge;
    for (int c = tid; c < nchunk; c += 1024) {
        const int rec = c >> 1;
        temp[2 * (size_t)sDst[rec] + (c & 1)] = sRec[c];
    }
}

// ---------------- Phase B: per-bucket fine sort (L2-local), 1024 threads ----------------
__global__ __launch_bounds__(1024) void partB_kernel(const int* __restrict__ cofs,
                                                     const u32x4* __restrict__ temp,
                                                     u32x4* __restrict__ payload,
                                                     int* __restrict__ rowst) {
    const int b = blockIdx.x;                 // grid = NBUCK
    const int t = threadIdx.x;
    const int start = cofs[b];
    const int endp = cofs[b + 1];
    __shared__ int lh[256];
    __shared__ int s[256];
    if (t < 256) lh[t] = 0;
    __syncthreads();
    for (int i = start + t; i < endp; i += 1024) {
        u32x4 q1 = temp[2 * (size_t)i + 1];   // plain load: warms L2 for pass 2
        atomicAdd(&lh[q1.w], 1);
    }
    __syncthreads();
    int v = 0;
    if (t < 256) {
        v = lh[t];
        s[t] = v;
    }
    __syncthreads();
    for (int off = 1; off < 256; off <<= 1) {
        int a = (t >= off && t < 256) ? s[t - off] : 0;
        __syncthreads();
        if (t < 256) s[t] += a;
        __syncthreads();
    }
    if (t < 256) {
        const int excl = s[t] - v;
        rowst[b * 256 + t] = start + excl;
        lh[t] = excl;                          // becomes per-row cursor
    }
    if (b == NBUCK - 1 && t == 0) rowst[NBUCK * 256] = endp;   // guard
    __syncthreads();
    for (int i = start + t; i < endp; i += 1024) {
        u32x4 q0 = temp[2 * (size_t)i];
        u32x4 q1 = temp[2 * (size_t)i + 1];
        const int rl = (int)q1.w;
        q1.w = 0u;
        const int pos = start + atomicAdd(&lh[rl], 1);   // random within ~131 KB -> L2
        payload[2 * (size_t)pos] = q0;
        payload[2 * (size_t)pos + 1] = q1;
    }
}

// ---------------- FUSED main pass: 16 rows/block; edge phase + MFMA epilogue ----------------
__global__ __launch_bounds__(256) void row6_kernel(const int* __restrict__ rowst,
                                                   const u32x4* __restrict__ payload,
                                                   const unsigned* __restrict__ Xh,
                                                   const h8f* __restrict__ Bpack,
                                                   const float* __restrict__ bias,
                                                   float* __restrict__ out) {
    __shared__ __half sY[2][16][200];          // 400 B row pitch: 2-way LDS alias only
    const int w = (int)threadIdx.x >> 6;       // wave id = 4 rows / nt quadrant
    const int lane = threadIdx.x & 63;
    const int band = blockIdx.x * 16;          // grid = 6250 exact

    for (int q = 0; q < 4; ++q) {
        const int ri = w * 4 + q;
        const int r = __builtin_amdgcn_readfirstlane(band + ri);
        const int start = rowst[r];
        const int end = rowst[r + 1];
        const int n = end - start;

        float aR0 = 0.f, aI0 = 0.f, aR1 = 0.f, aI1 = 0.f, aR2 = 0.f, aI2 = 0.f;

        auto gx = [&](unsigned col) -> unsigned { return Xh[(size_t)col * 64 + lane]; };
        auto accum = [&](const u32x4& q0, const u32x4& q1, unsigned xv) {
            aR0 = fdot2h(q0.y, xv, aR0);
            aI0 = fdot2h(q0.z, xv, aI0);
            aR1 = fdot2h(q0.w, xv, aR1);
            aI1 = fdot2h(q1.x, xv, aI1);
            aR2 = fdot2h(q1.y, xv, aR2);
            aI2 = fdot2h(q1.z, xv, aI2);
        };

        if (n >= 8) {
            int p = start;
            u32x4 A0 = payload[2 * (size_t)p], A1 = payload[2 * (size_t)p + 1];
            u32x4 B0 = payload[2 * (size_t)(p + 1)], B1 = payload[2 * (size_t)(p + 1) + 1];
            u32x4 C0 = payload[2 * (size_t)(p + 2)], C1 = payload[2 * (size_t)(p + 2) + 1];
            u32x4 D0 = payload[2 * (size_t)(p + 3)], D1 = payload[2 * (size_t)(p + 3) + 1];
            u32x4 E0 = payload[2 * (size_t)(p + 4)], E1 = payload[2 * (size_t)(p + 4) + 1];
            u32x4 F0 = payload[2 * (size_t)(p + 5)], F1 = payload[2 * (size_t)(p + 5) + 1];
            unsigned xA = gx(A0.x), xB = gx(B0.x), xC = gx(C0.x), xD = gx(D0.x);

            for (; p + 7 < end; p += 2) {
                u32x4 G0 = payload[2 * (size_t)(p + 6)], G1 = payload[2 * (size_t)(p + 6) + 1];
                u32x4 H0 = payload[2 * (size_t)(p + 7)], H1 = payload[2 * (size_t)(p + 7) + 1];
                unsigned xE = gx(E0.x);
                unsigned xF = gx(F0.x);
                accum(A0, A1, xA);
                accum(B0, B1, xB);
                A0 = C0; A1 = C1; xA = xC;
                B0 = D0; B1 = D1; xB = xD;
                C0 = E0; C1 = E1; xC = xE;
                D0 = F0; D1 = F1; xD = xF;
                E0 = G0; E1 = G1;
                F0 = H0; F1 = H1;
            }
            accum(A0, A1, xA);
            accum(B0, B1, xB);
            accum(C0, C1, xC);
            accum(D0, D1, xD);
            unsigned xE = gx(E0.x);
            unsigned xF = gx(F0.x);
            accum(E0, E1, xE);
            accum(F0, F1, xF);
            if (p + 6 < end) {
                u32x4 G0 = payload[2 * (size_t)(p + 6)], G1 = payload[2 * (size_t)(p + 6) + 1];
                unsigned xG = gx(G0.x);
                accum(G0, G1, xG);
            }
        } else {
            for (int p = start; p < end; ++p) {
                u32x4 q0 = payload[2 * (size_t)p], q1 = payload[2 * (size_t)p + 1];
                unsigned xv = gx(q0.x);
                accum(q0, q1, xv);
            }
        }

        sY[0][ri][lane] = __float2half(aR0);
        sY[0][ri][64 + lane] = __float2half(aR1);
        sY[0][ri][128 + lane] = __float2half(aR2);
        sY[1][ri][lane] = __float2half(aI0);
        sY[1][ri][64 + lane] = __float2half(aI1);
        sY[1][ri][128 + lane] = __float2half(aI2);
    }
    __syncthreads();

    // MFMA epilogue: wave w = column quadrant nt = w.
    const int nt = w;
    const int m = lane & 15;
    const int ko = (lane >> 4) << 3;
    f32x4 accR = (f32x4){0.f, 0.f, 0.f, 0.f};
    f32x4 accI = (f32x4){0.f, 0.f, 0.f, 0.f};
#pragma unroll
    for (int kc = 0; kc < 6; ++kc) {
        h8f bf = Bpack[(kc * 4 + nt) * 64 + lane];                    // L3-hot, 16 B/lane
        h8f aR = *(const h8f*)&sY[0][m][kc * 32 + ko];
        h8f aI = *(const h8f*)&sY[1][m][kc * 32 + ko];
        accR = __builtin_amdgcn_mfma_f32_16x16x32_f16(aR, bf, accR, 0, 0, 0);
        accI = __builtin_amdgcn_mfma_f32_16x16x32_f16(aI, bf, accI, 0, 0, 0);
    }
    const int colw = lane & 15;
    const int rbase = (lane >> 4) << 2;
    const float b = bias[nt * 16 + colw];
#pragma unroll
    for (int rr = 0; rr < 4; ++rr) {
        const int row = band + rbase + rr;
        __builtin_nontemporal_store(accR[rr] + b,
                                    &out[(size_t)row * 64 + nt * 16 + colw]);
        __builtin_nontemporal_store(accI[rr] + b,
                                    &out[(size_t)(N_NODES + row) * 64 + nt * 16 + colw]);
    }
}

// ================= Fallback kernels (small-ws paths) =================
template <int NK>
__global__ __launch_bounds__(256) void xw_kernel(const float* __restrict__ Xr,
                                                 const float* __restrict__ Xi,
                                                 const float* __restrict__ W,
                                                 __half2* __restrict__ XWh) {
    __shared__ float sW[NK][64][64];
    __shared__ float4 sX4[2][32][16];
    const int tid = threadIdx.x;

    float4* swf = (float4*)&sW[0][0][0];
    const float4* gW = (const float4*)W;
    for (int i = tid; i < NK * 1024; i += 256) swf[i] = gW[i];

    const int rowbase = blockIdx.x * 32;
    float4* sxf = (float4*)sX4;
    const float4* gXr = (const float4*)(Xr + (size_t)rowbase * CH);
    const float4* gXi = (const float4*)(Xi + (size_t)rowbase * CH);
    for (int i = tid; i < 512; i += 256) {
        sxf[i] = gXr[i];
        sxf[512 + i] = gXi[i];
    }
    __syncthreads();

    const int col = tid & 63;
    const int rg = tid >> 6;

    float acc[8][2 * NK];
#pragma unroll
    for (int i = 0; i < 8; ++i)
#pragma unroll
        for (int c2 = 0; c2 < 2 * NK; ++c2) acc[i][c2] = 0.0f;

#pragma unroll 2
    for (int j4 = 0; j4 < 16; ++j4) {
        float w[NK][4];
#pragma unroll
        for (int k = 0; k < NK; ++k)
#pragma unroll
            for (int jj = 0; jj < 4; ++jj) w[k][jj] = sW[k][j4 * 4 + jj][col];
#pragma unroll
        for (int i = 0; i < 8; ++i) {
            float4 xr = sX4[0][rg * 8 + i][j4];
            float4 xi = sX4[1][rg * 8 + i][j4];
            const float xra[4] = {xr.x, xr.y, xr.z, xr.w};
            const float xia[4] = {xi.x, xi.y, xi.z, xi.w};
#pragma unroll
            for (int jj = 0; jj < 4; ++jj)
#pragma unroll
                for (int k = 0; k < NK; ++k) {
                    acc[i][2 * k] += xra[jj] * w[k][jj];
                    acc[i][2 * k + 1] += xia[jj] * w[k][jj];
                }
        }
    }

#pragma unroll
    for (int i = 0; i < 8; ++i) {
        __half2* dst = XWh + (size_t)(rowbase + rg * 8 + i) * (NK * 64);
#pragma unroll
        for (int k = 0; k < NK; ++k)
            dst[k * 64 + col] = __floats2half2_rn(acc[i][2 * k], acc[i][2 * k + 1]);
    }
}

template <int NK>
__global__ __launch_bounds__(256) void edge_kernel(const int* __restrict__ rows,
                                                   const int* __restrict__ cols,
                                                   const float* __restrict__ Lr,
                                                   const float* __restrict__ Li,
                                                   const __half2* __restrict__ XWh,
                                                   float* __restrict__ out) {
    const int gid = blockIdx.x * 256 + threadIdx.x;
    const int e = gid >> 6;
    const int lane = gid & 63;
    if (e >= E_EDGES) return;

    const int row = rows[e];
    const int colN = cols[e];
    const __half2* xw = XWh + (size_t)colN * (NK * 64);

    float rc = 0.0f, ic = 0.0f;
#pragma unroll
    for (int k = 0; k < NK; ++k) {
        const float lr = Lr[(size_t)k * E_EDGES + e];
        const float li = Li[(size_t)k * E_EDGES + e];
        float2 v = __half22float2(xw[k * 64 + lane]);
        rc += lr * v.x - li * v.y;
        ic += li * v.x + lr * v.y;
    }
    unsafeAtomicAdd(out + (size_t)row * 64 + lane, rc);
    unsafeAtomicAdd(out + ((size_t)N_NODES + row) * 64 + lane, ic);
}

extern "C" void kernel_launch(void* const* d_in, const int* in_sizes, int n_in,
                              void* d_out, int out_size, void* d_ws, size_t ws_size,
                              hipStream_t stream) {
    const float* Xr = (const float*)d_in[0];
    const float* Xi = (const float*)d_in[1];
    const int* ei = (const int*)d_in[2];
    const float* Lr = (const float*)d_in[3];
    const float* Li = (const float*)d_in[4];
    const float* W = (const float*)d_in[5];
    const float* bias = (const float*)d_in[6];
    float* out = (float*)d_out;

    const int* rows = ei;
    const int* cols = ei + E_EDGES;

    char* wsb = (char*)d_ws;
    const int edge_grid = (int)((size_t)E_EDGES * 64 / 256);      // 400000
    const int gemm_grid = N_NODES / 32;                           // 3125

    // Main-path ws layout
    unsigned* Xh = (unsigned*)wsb;                                //  25,600,000 B
    unsigned* payload = (unsigned*)(wsb + 25600000);              //  51,200,000 B (32 B/edge)
    u32x4* temp = (u32x4*)(wsb + 76800000);                       //  51,200,000 B
    int* rowst = (int*)(wsb + 128000000);                         //     404,480 B (NP+1 used)
    int* bcnt = (int*)(wsb + 128404480);                          //       1,600 B
    int* cofs = (int*)(wsb + 128406080);                          //       1,600 B
    int* ccur = (int*)(wsb + 128407680);                          //       1,600 B
    h8f* Bpack = (h8f*)(wsb + 128409280);                         //      24,576 B
    const size_t need_new = 128433856;

    if (ws_size >= need_new) {
        xh_zero_kernel<<<6250, 256, 0, stream>>>(Xr, Xi, Xh, bcnt);
        chist_kernel<<<NBLK_A, 1024, 0, stream>>>(rows, bcnt);
        cscan_kernel<<<1, 512, 0, stream>>>(bcnt, cofs, ccur, W, Bpack);
        partA_kernel<<<NBLK_A, 1024, 0, stream>>>(rows, cols, Lr, Li, ccur, temp);
        partB_kernel<<<NBUCK, 1024, 0, stream>>>(cofs, temp, (u32x4*)payload, rowst);
        row6_kernel<<<N_NODES / 16, 256, 0, stream>>>(rowst, (const u32x4*)payload, Xh,
                                                      Bpack, bias, out);
        return;
    }

    // Fallback ws layout (atomic edge scatter over XWh table)
    __half2* XWh = (__half2*)wsb;                                 //  76,800,000 B
    const size_t need_onepass = 76800000;

    if (ws_size >= need_onepass) {
        init_out_kernel<<<2 * N_NODES * CH / 256, 256, 0, stream>>>(bias, out);
        xw_kernel<3><<<gemm_grid, 256, 0, stream>>>(Xr, Xi, W, XWh);
        edge_kernel<3><<<edge_grid, 256, 0, stream>>>(rows, cols, Lr, Li, XWh, out);
    } else {
        init_out_kernel<<<2 * N_NODES * CH / 256, 256, 0, stream>>>(bias, out);
        for (int k = 0; k < 3; ++k) {
            xw_kernel<1><<<gemm_grid, 256, 0, stream>>>(Xr, Xi, W + (size_t)k * 4096, XWh);
            edge_kernel<1><<<edge_grid, 256, 0, stream>>>(rows, cols,
                                                          Lr + (size_t)k * E_EDGES,
                                                          Li + (size_t)k * E_EDGES, XWh, out);
        }
    }
}

// Round 18
// 160.587 us; speedup vs baseline: 1.3541x; 1.1116x over previous
//
#include <hip/hip_runtime.h>
#include <hip/hip_fp16.h>

// SDConv on MI355X.
// Reference: out = sum_k spmm(L_k, X) @ W_k + bias  (complex).
// Structure: apply W AFTER the spmm (k-expansion lives in the L domain), so the
// gather table is just X: 25.6 MB fp16 -> L2/L3-resident.
//   1. xh_zero_kernel: Xh[node][ch] = half2(Xr, Xi); zero coarse-bucket counters.
//   2. Hierarchical CSR build (random-64B-line writeback amplification R9/R10/R12;
//      occupancy R13/R15; NT-load lesson R16). Records are 16 B (R18: L swizzles
//      moved to the scalar pipe, halving all build/payload streams):
//      {col | (row&255)<<17, h2(lr0,li0), h2(lr1,li1), h2(lr2,li2)}.
//      chist -> cscan(+Wpack) -> partA (LDS radix partition, coalesced copy-out)
//      -> partB (per-bucket fine sort, L2-local, 1024-thr; emits rowst).
//   3. row6_kernel (FUSED row pass + output GEMM): block = 16 rows; 4 waves x 4
//      rows, 6-slot scalar payload pipeline / 4 gathers in flight; per edge the
//      (lr,-li)/(li,lr) operands are derived with s_xor/rot16; 6 dot2/edge; Y in
//      LDS (400 B pitch); barrier; MFMA per 16-col quadrant; NT-stores out + bias.

constexpr int N_NODES = 100000;
constexpr int E_EDGES = 1600000;
constexpr int CH = 64;
constexpr int NP = 100096;          // N padded to multiple of 256
constexpr int NBUCK = NP / 256;     // 391 coarse buckets (256 rows each)
constexpr int CHUNK_A = 2048;       // edges per partition block
constexpr int NBLK_A = (E_EDGES + CHUNK_A - 1) / CHUNK_A;   // 782
constexpr unsigned COLMASK = 0x1FFFFu;

typedef unsigned u32x4 __attribute__((ext_vector_type(4)));
typedef _Float16 h2f __attribute__((ext_vector_type(2)));
typedef _Float16 h8f __attribute__((ext_vector_type(8)));
typedef float f32x4 __attribute__((ext_vector_type(4)));

// f32 += dot(half2, half2) with f32 accumulation (v_dot2_f32_f16).
__device__ __forceinline__ float fdot2h(unsigned a, unsigned b, float c) {
#if __has_builtin(__builtin_amdgcn_fdot2)
    return __builtin_amdgcn_fdot2(__builtin_bit_cast(h2f, a),
                                  __builtin_bit_cast(h2f, b), c, false);
#else
    float2 af = __half22float2(__builtin_bit_cast(__half2, a));
    float2 bf = __half22float2(__builtin_bit_cast(__half2, b));
    return c + af.x * bf.x + af.y * bf.y;
#endif
}

__device__ __forceinline__ unsigned pack2(float a, float b) {
    return __builtin_bit_cast(unsigned, __floats2half2_rn(a, b));
}

__device__ __forceinline__ unsigned rot16(unsigned u) {
    return (u >> 16) | (u << 16);
}

__global__ __launch_bounds__(256) void init_out_kernel(const float* __restrict__ bias,
                                                       float* __restrict__ out) {
    int i = blockIdx.x * 256 + threadIdx.x;
    out[i] = bias[i & 63];
}

// ---------------- Phase 1: Xh = half2(Xr, Xi), [N][64]; zero bucket counters ----------------
__global__ __launch_bounds__(256) void xh_zero_kernel(const float* __restrict__ Xr,
                                                      const float* __restrict__ Xi,
                                                      unsigned* __restrict__ Xh,
                                                      int* __restrict__ bcnt) {
    int i = blockIdx.x * 256 + threadIdx.x;   // grid = N*64/4/256 = 6250 exact
    if (i < NBUCK) bcnt[i] = 0;
    const float4 r = ((const float4*)Xr)[i];
    const float4 m = ((const float4*)Xi)[i];
    uint4 u;
    u.x = pack2(r.x, m.x);
    u.y = pack2(r.y, m.y);
    u.z = pack2(r.z, m.z);
    u.w = pack2(r.w, m.w);
    ((uint4*)Xh)[i] = u;
}

// ---------------- Coarse bucket histogram ----------------
__global__ __launch_bounds__(1024) void chist_kernel(const int* __restrict__ rows,
                                                     int* __restrict__ bcnt) {
    __shared__ int lh[NBUCK];
    const int tid = threadIdx.x;
    for (int t = tid; t < NBUCK; t += 1024) lh[t] = 0;
    __syncthreads();
    const int base = blockIdx.x * CHUNK_A;
    const int nedge = min(CHUNK_A, E_EDGES - base);
    for (int j = tid; j < nedge; j += 1024) atomicAdd(&lh[rows[base + j] >> 8], 1);
    __syncthreads();
    for (int t = tid; t < NBUCK; t += 1024)
        if (lh[t]) atomicAdd(&bcnt[t], lh[t]);
}

// ---------------- Scan of 391 bucket counts + W pack (single block) ----------------
// Bpack[(kc*4+nt)*64 + L] = 8 halves: W[kc*32 + (L>>4)*8 + j][nt*16 + (L&15)]
__global__ __launch_bounds__(512) void cscan_kernel(const int* __restrict__ bcnt,
                                                    int* __restrict__ cofs,
                                                    int* __restrict__ ccur,
                                                    const float* __restrict__ W,
                                                    h8f* __restrict__ Bpack) {
    __shared__ int s[512];
    const int t = threadIdx.x;
    int v = (t < NBUCK) ? bcnt[t] : 0;
    s[t] = v;
    __syncthreads();
    for (int off = 1; off < 512; off <<= 1) {
        int a = (t >= off) ? s[t - off] : 0;
        __syncthreads();
        s[t] += a;
        __syncthreads();
    }
    if (t < NBUCK) {
        cofs[t] = s[t] - v;
        ccur[t] = s[t] - v;
    }
    if (t == NBUCK - 1) cofs[NBUCK] = s[t];   // == E_EDGES

    // W -> MFMA B-fragment pack (independent of scan)
    for (int sidx = t; sidx < 24 * 64; sidx += 512) {
        const int L = sidx & 63;
        const int ntkc = sidx >> 6;
        const int nt = ntkc & 3;
        const int kc = ntkc >> 2;
        const int colb = nt * 16 + (L & 15);
        const int kbase = kc * 32 + ((L >> 4) << 3);
        h8f vv;
#pragma unroll
        for (int j = 0; j < 8; ++j) vv[j] = (_Float16)W[(kbase + j) * 64 + colb];
        Bpack[sidx] = vv;
    }
}

// ---------------- Phase A: LDS-staged radix partition, coalesced copy-out ----------------
// record (16 B): {col | (row&255)<<17, h2(lr0,li0), h2(lr1,li1), h2(lr2,li2)}
__global__ __launch_bounds__(1024) void partA_kernel(const int* __restrict__ rows,
                                                     const int* __restrict__ cols,
                                                     const float* __restrict__ Lr,
                                                     const float* __restrict__ Li,
                                                     int* __restrict__ ccur,
                                                     u32x4* __restrict__ temp) {
    __shared__ u32x4 sRec[CHUNK_A];       // 32,768 B, bucket-sorted records
    __shared__ int sDst[CHUNK_A];         //  8,192 B, global record index per record
    __shared__ int lh[NBUCK];
    __shared__ int lcur[NBUCK];
    __shared__ int gdel[NBUCK];           // global base - LDS base
    __shared__ int ss[512];
    const int tid = threadIdx.x;
    const int base = blockIdx.x * CHUNK_A;
    const int nedge = min(CHUNK_A, E_EDGES - base);

    for (int t = tid; t < NBUCK; t += 1024) lh[t] = 0;
    __syncthreads();
    for (int j = tid; j < nedge; j += 1024) atomicAdd(&lh[rows[base + j] >> 8], 1);
    __syncthreads();

    if (tid < 512) ss[tid] = (tid < NBUCK) ? lh[tid] : 0;
    __syncthreads();
    for (int off = 1; off < 512; off <<= 1) {
        int a = 0;
        if (tid < 512 && tid >= off) a = ss[tid - off];
        __syncthreads();
        if (tid < 512) ss[tid] += a;
        __syncthreads();
    }
    if (tid < NBUCK) {
        const int excl = ss[tid] - lh[tid];
        lcur[tid] = excl;
        const int gb = lh[tid] ? atomicAdd(&ccur[tid], lh[tid]) : 0;
        gdel[tid] = gb - excl;            // one global atomic per (block,bucket)
    }
    __syncthreads();

    for (int j = tid; j < nedge; j += 1024) {
        const int e = base + j;
        const int r = rows[e];
        const int bk = r >> 8;
        const int pos = atomicAdd(&lcur[bk], 1);
        u32x4 u;
        u.x = (unsigned)cols[e] | ((unsigned)(r & 255) << 17);
        u.y = pack2(Lr[e], Li[e]);
        u.z = pack2(Lr[E_EDGES + e], Li[E_EDGES + e]);
        u.w = pack2(Lr[2 * E_EDGES + e], Li[2 * E_EDGES + e]);
        sRec[pos] = u;
        sDst[pos] = gdel[bk] + pos;       // global record index
    }
    __syncthreads();

    // Coalesced copy-out: bucket-sorted LDS order -> piecewise-consecutive dests.
    for (int c = tid; c < nedge; c += 1024) temp[sDst[c]] = sRec[c];
}

// ---------------- Phase B: per-bucket fine sort (L2-local), 1024 threads ----------------
__global__ __launch_bounds__(1024) void partB_kernel(const int* __restrict__ cofs,
                                                     const u32x4* __restrict__ temp,
                                                     u32x4* __restrict__ payload,
                                                     int* __restrict__ rowst) {
    const int b = blockIdx.x;                 // grid = NBUCK
    const int t = threadIdx.x;
    const int start = cofs[b];
    const int endp = cofs[b + 1];
    __shared__ int lh[256];
    __shared__ int s[256];
    if (t < 256) lh[t] = 0;
    __syncthreads();
    for (int i = start + t; i < endp; i += 1024)
        atomicAdd(&lh[temp[i].x >> 17], 1);   // warms L2 for pass 2
    __syncthreads();
    int v = 0;
    if (t < 256) {
        v = lh[t];
        s[t] = v;
    }
    __syncthreads();
    for (int off = 1; off < 256; off <<= 1) {
        int a = (t >= off && t < 256) ? s[t - off] : 0;
        __syncthreads();
        if (t < 256) s[t] += a;
        __syncthreads();
    }
    if (t < 256) {
        const int excl = s[t] - v;
        rowst[b * 256 + t] = start + excl;
        lh[t] = excl;                          // becomes per-row cursor
    }
    if (b == NBUCK - 1 && t == 0) rowst[NBUCK * 256] = endp;   // guard
    __syncthreads();
    for (int i = start + t; i < endp; i += 1024) {
        u32x4 q = temp[i];
        const int rl = (int)(q.x >> 17);
        const int pos = start + atomicAdd(&lh[rl], 1);   // random within ~66 KB -> L2
        payload[pos] = q;
    }
}

// ---------------- FUSED main pass: 16 rows/block; edge phase + MFMA epilogue ----------------
__global__ __launch_bounds__(256) void row6_kernel(const int* __restrict__ rowst,
                                                   const u32x4* __restrict__ payload,
                                                   const unsigned* __restrict__ Xh,
                                                   const h8f* __restrict__ Bpack,
                                                   const float* __restrict__ bias,
                                                   float* __restrict__ out) {
    __shared__ __half sY[2][16][200];          // 400 B row pitch: 2-way LDS alias only
    const int w = (int)threadIdx.x >> 6;       // wave id = 4 rows / nt quadrant
    const int lane = threadIdx.x & 63;
    const int band = blockIdx.x * 16;          // grid = 6250 exact

    for (int q = 0; q < 4; ++q) {
        const int ri = w * 4 + q;
        const int r = __builtin_amdgcn_readfirstlane(band + ri);
        const int start = rowst[r];
        const int end = rowst[r + 1];
        const int n = end - start;

        float aR0 = 0.f, aI0 = 0.f, aR1 = 0.f, aI1 = 0.f, aR2 = 0.f, aI2 = 0.f;

        auto gx = [&](unsigned cw) -> unsigned {
            return Xh[(size_t)(cw & COLMASK) * 64 + lane];
        };
        auto accum = [&](const u32x4& qq, unsigned xv) {
            // (lr,-li) = L ^ 0x80000000 ; (li,lr) = rot16(L) — scalar-pipe derivations
            aR0 = fdot2h(qq.y ^ 0x80000000u, xv, aR0);
            aI0 = fdot2h(rot16(qq.y), xv, aI0);
            aR1 = fdot2h(qq.z ^ 0x80000000u, xv, aR1);
            aI1 = fdot2h(rot16(qq.z), xv, aI1);
            aR2 = fdot2h(qq.w ^ 0x80000000u, xv, aR2);
            aI2 = fdot2h(rot16(qq.w), xv, aI2);
        };

        if (n >= 8) {
            int p = start;
            u32x4 A = payload[p];
            u32x4 B = payload[p + 1];
            u32x4 C = payload[p + 2];
            u32x4 D = payload[p + 3];
            u32x4 E = payload[p + 4];
            u32x4 F = payload[p + 5];
            unsigned xA = gx(A.x), xB = gx(B.x), xC = gx(C.x), xD = gx(D.x);

            for (; p + 7 < end; p += 2) {
                u32x4 G = payload[p + 6];
                u32x4 H = payload[p + 7];
                unsigned xE = gx(E.x);
                unsigned xF = gx(F.x);
                accum(A, xA);
                accum(B, xB);
                A = C; xA = xC;
                B = D; xB = xD;
                C = E; xC = xE;
                D = F; xD = xF;
                E = G;
                F = H;
            }
            accum(A, xA);
            accum(B, xB);
            accum(C, xC);
            accum(D, xD);
            unsigned xE = gx(E.x);
            unsigned xF = gx(F.x);
            accum(E, xE);
            accum(F, xF);
            if (p + 6 < end) {
                u32x4 G = payload[p + 6];
                unsigned xG = gx(G.x);
                accum(G, xG);
            }
        } else {
            for (int p = start; p < end; ++p) {
                u32x4 qq = payload[p];
                unsigned xv = gx(qq.x);
                accum(qq, xv);
            }
        }

        sY[0][ri][lane] = __float2half(aR0);
        sY[0][ri][64 + lane] = __float2half(aR1);
        sY[0][ri][128 + lane] = __float2half(aR2);
        sY[1][ri][lane] = __float2half(aI0);
        sY[1][ri][64 + lane] = __float2half(aI1);
        sY[1][ri][128 + lane] = __float2half(aI2);
    }
    __syncthreads();

    // MFMA epilogue: wave w = column quadrant nt = w.
    const int nt = w;
    const int m = lane & 15;
    const int ko = (lane >> 4) << 3;
    f32x4 accR = (f32x4){0.f, 0.f, 0.f, 0.f};
    f32x4 accI = (f32x4){0.f, 0.f, 0.f, 0.f};
#pragma unroll
    for (int kc = 0; kc < 6; ++kc) {
        h8f bf = Bpack[(kc * 4 + nt) * 64 + lane];                    // L3-hot, 16 B/lane
        h8f aR = *(const h8f*)&sY[0][m][kc * 32 + ko];
        h8f aI = *(const h8f*)&sY[1][m][kc * 32 + ko];
        accR = __builtin_amdgcn_mfma_f32_16x16x32_f16(aR, bf, accR, 0, 0, 0);
        accI = __builtin_amdgcn_mfma_f32_16x16x32_f16(aI, bf, accI, 0, 0, 0);
    }
    const int colw = lane & 15;
    const int rbase = (lane >> 4) << 2;
    const float b = bias[nt * 16 + colw];
#pragma unroll
    for (int rr = 0; rr < 4; ++rr) {
        const int row = band + rbase + rr;
        __builtin_nontemporal_store(accR[rr] + b,
                                    &out[(size_t)row * 64 + nt * 16 + colw]);
        __builtin_nontemporal_store(accI[rr] + b,
                                    &out[(size_t)(N_NODES + row) * 64 + nt * 16 + colw]);
    }
}

// ================= Fallback kernels (small-ws paths) =================
template <int NK>
__global__ __launch_bounds__(256) void xw_kernel(const float* __restrict__ Xr,
                                                 const float* __restrict__ Xi,
                                                 const float* __restrict__ W,
                                                 __half2* __restrict__ XWh) {
    __shared__ float sW[NK][64][64];
    __shared__ float4 sX4[2][32][16];
    const int tid = threadIdx.x;

    float4* swf = (float4*)&sW[0][0][0];
    const float4* gW = (const float4*)W;
    for (int i = tid; i < NK * 1024; i += 256) swf[i] = gW[i];

    const int rowbase = blockIdx.x * 32;
    float4* sxf = (float4*)sX4;
    const float4* gXr = (const float4*)(Xr + (size_t)rowbase * CH);
    const float4* gXi = (const float4*)(Xi + (size_t)rowbase * CH);
    for (int i = tid; i < 512; i += 256) {
        sxf[i] = gXr[i];
        sxf[512 + i] = gXi[i];
    }
    __syncthreads();

    const int col = tid & 63;
    const int rg = tid >> 6;

    float acc[8][2 * NK];
#pragma unroll
    for (int i = 0; i < 8; ++i)
#pragma unroll
        for (int c2 = 0; c2 < 2 * NK; ++c2) acc[i][c2] = 0.0f;

#pragma unroll 2
    for (int j4 = 0; j4 < 16; ++j4) {
        float w[NK][4];
#pragma unroll
        for (int k = 0; k < NK; ++k)
#pragma unroll
            for (int jj = 0; jj < 4; ++jj) w[k][jj] = sW[k][j4 * 4 + jj][col];
#pragma unroll
        for (int i = 0; i < 8; ++i) {
            float4 xr = sX4[0][rg * 8 + i][j4];
            float4 xi = sX4[1][rg * 8 + i][j4];
            const float xra[4] = {xr.x, xr.y, xr.z, xr.w};
            const float xia[4] = {xi.x, xi.y, xi.z, xi.w};
#pragma unroll
            for (int jj = 0; jj < 4; ++jj)
#pragma unroll
                for (int k = 0; k < NK; ++k) {
                    acc[i][2 * k] += xra[jj] * w[k][jj];
                    acc[i][2 * k + 1] += xia[jj] * w[k][jj];
                }
        }
    }

#pragma unroll
    for (int i = 0; i < 8; ++i) {
        __half2* dst = XWh + (size_t)(rowbase + rg * 8 + i) * (NK * 64);
#pragma unroll
        for (int k = 0; k < NK; ++k)
            dst[k * 64 + col] = __floats2half2_rn(acc[i][2 * k], acc[i][2 * k + 1]);
    }
}

template <int NK>
__global__ __launch_bounds__(256) void edge_kernel(const int* __restrict__ rows,
                                                   const int* __restrict__ cols,
                                                   const float* __restrict__ Lr,
                                                   const float* __restrict__ Li,
                                                   const __half2* __restrict__ XWh,
                                                   float* __restrict__ out) {
    const int gid = blockIdx.x * 256 + threadIdx.x;
    const int e = gid >> 6;
    const int lane = gid & 63;
    if (e >= E_EDGES) return;

    const int row = rows[e];
    const int colN = cols[e];
    const __half2* xw = XWh + (size_t)colN * (NK * 64);

    float rc = 0.0f, ic = 0.0f;
#pragma unroll
    for (int k = 0; k < NK; ++k) {
        const float lr = Lr[(size_t)k * E_EDGES + e];
        const float li = Li[(size_t)k * E_EDGES + e];
        float2 v = __half22float2(xw[k * 64 + lane]);
        rc += lr * v.x - li * v.y;
        ic += li * v.x + lr * v.y;
    }
    unsafeAtomicAdd(out + (size_t)row * 64 + lane, rc);
    unsafeAtomicAdd(out + ((size_t)N_NODES + row) * 64 + lane, ic);
}

extern "C" void kernel_launch(void* const* d_in, const int* in_sizes, int n_in,
                              void* d_out, int out_size, void* d_ws, size_t ws_size,
                              hipStream_t stream) {
    const float* Xr = (const float*)d_in[0];
    const float* Xi = (const float*)d_in[1];
    const int* ei = (const int*)d_in[2];
    const float* Lr = (const float*)d_in[3];
    const float* Li = (const float*)d_in[4];
    const float* W = (const float*)d_in[5];
    const float* bias = (const float*)d_in[6];
    float* out = (float*)d_out;

    const int* rows = ei;
    const int* cols = ei + E_EDGES;

    char* wsb = (char*)d_ws;
    const int edge_grid = (int)((size_t)E_EDGES * 64 / 256);      // 400000
    const int gemm_grid = N_NODES / 32;                           // 3125

    // Main-path ws layout (16 B records)
    unsigned* Xh = (unsigned*)wsb;                                //  25,600,000 B
    unsigned* payload = (unsigned*)(wsb + 25600000);              //  25,600,000 B (16 B/edge)
    u32x4* temp = (u32x4*)(wsb + 51200000);                       //  25,600,000 B
    int* rowst = (int*)(wsb + 76800000);                          //     404,480 B (NP+1 used)
    int* bcnt = (int*)(wsb + 77204480);                           //       1,600 B
    int* cofs = (int*)(wsb + 77206080);                           //       1,600 B
    int* ccur = (int*)(wsb + 77207680);                           //       1,600 B
    h8f* Bpack = (h8f*)(wsb + 77209280);                          //      24,576 B
    const size_t need_new = 77233856;

    if (ws_size >= need_new) {
        xh_zero_kernel<<<6250, 256, 0, stream>>>(Xr, Xi, Xh, bcnt);
        chist_kernel<<<NBLK_A, 1024, 0, stream>>>(rows, bcnt);
        cscan_kernel<<<1, 512, 0, stream>>>(bcnt, cofs, ccur, W, Bpack);
        partA_kernel<<<NBLK_A, 1024, 0, stream>>>(rows, cols, Lr, Li, ccur, temp);
        partB_kernel<<<NBUCK, 1024, 0, stream>>>(cofs, temp, (u32x4*)payload, rowst);
        row6_kernel<<<N_NODES / 16, 256, 0, stream>>>(rowst, (const u32x4*)payload, Xh,
                                                      Bpack, bias, out);
        return;
    }

    // Fallback ws layout (atomic edge scatter over XWh table)
    __half2* XWh = (__half2*)wsb;                                 //  76,800,000 B
    const size_t need_onepass = 76800000;

    if (ws_size >= need_onepass) {
        init_out_kernel<<<2 * N_NODES * CH / 256, 256, 0, stream>>>(bias, out);
        xw_kernel<3><<<gemm_grid, 256, 0, stream>>>(Xr, Xi, W, XWh);
        edge_kernel<3><<<edge_grid, 256, 0, stream>>>(rows, cols, Lr, Li, XWh, out);
    } else {
        init_out_kernel<<<2 * N_NODES * CH / 256, 256, 0, stream>>>(bias, out);
        for (int k = 0; k < 3; ++k) {
            xw_kernel<1><<<gemm_grid, 256, 0, stream>>>(Xr, Xi, W + (size_t)k * 4096, XWh);
            edge_kernel<1><<<edge_grid, 256, 0, stream>>>(rows, cols,
                                                          Lr + (size_t)k * E_EDGES,
                                                          Li + (size_t)k * E_EDGES, XWh, out);
        }
    }
}

// Round 19
// 156.614 us; speedup vs baseline: 1.3884x; 1.0254x over previous
//
#include <hip/hip_runtime.h>
#include <hip/hip_fp16.h>

// SDConv on MI355X.
// Reference: out = sum_k spmm(L_k, X) @ W_k + bias  (complex).
// Structure: apply W AFTER the spmm (k-expansion lives in the L domain), so the
// gather table is just X: 25.6 MB fp16 -> L2/L3-resident.
//   1. prep_hist_kernel: Xh[node][ch] = half2(Xr, Xi) AND coarse bucket histogram
//      (1.6M float4 items == 1.6M edges; one fused pass). bcnt zeroed by memset.
//   2. Hierarchical CSR build (random-64B-line writeback amplification R9/R10/R12;
//      occupancy R13/R15; NT-load lesson R16; 16 B records R18):
//      cscan(+Wpack) -> partA (LDS radix partition, coalesced copy-out) ->
//      partB (per-bucket fine sort, L2-local, 1024-thr; emits rowst).
//   3. row6_kernel (FUSED row pass + output GEMM): block = 16 rows; 4 waves x 4
//      rows; 8-slot scalar payload pipeline with 8 X-gathers in flight (R19:
//      doubled MLP), 4 edges/iter; (lr,-li)/(li,lr) derived via s_xor/rot16;
//      6 dot2/edge; Y in LDS (400 B pitch); MFMA per 16-col quadrant; NT-stores.

constexpr int N_NODES = 100000;
constexpr int E_EDGES = 1600000;
constexpr int CH = 64;
constexpr int NP = 100096;          // N padded to multiple of 256
constexpr int NBUCK = NP / 256;     // 391 coarse buckets (256 rows each)
constexpr int CHUNK_A = 2048;       // edges per partition block
constexpr int NBLK_A = (E_EDGES + CHUNK_A - 1) / CHUNK_A;   // 782
constexpr unsigned COLMASK = 0x1FFFFu;

typedef unsigned u32x4 __attribute__((ext_vector_type(4)));
typedef _Float16 h2f __attribute__((ext_vector_type(2)));
typedef _Float16 h8f __attribute__((ext_vector_type(8)));
typedef float f32x4 __attribute__((ext_vector_type(4)));

// f32 += dot(half2, half2) with f32 accumulation (v_dot2_f32_f16).
__device__ __forceinline__ float fdot2h(unsigned a, unsigned b, float c) {
#if __has_builtin(__builtin_amdgcn_fdot2)
    return __builtin_amdgcn_fdot2(__builtin_bit_cast(h2f, a),
                                  __builtin_bit_cast(h2f, b), c, false);
#else
    float2 af = __half22float2(__builtin_bit_cast(__half2, a));
    float2 bf = __half22float2(__builtin_bit_cast(__half2, b));
    return c + af.x * bf.x + af.y * bf.y;
#endif
}

__device__ __forceinline__ unsigned pack2(float a, float b) {
    return __builtin_bit_cast(unsigned, __floats2half2_rn(a, b));
}

__device__ __forceinline__ unsigned rot16(unsigned u) {
    return (u >> 16) | (u << 16);
}

__global__ __launch_bounds__(256) void init_out_kernel(const float* __restrict__ bias,
                                                       float* __restrict__ out) {
    int i = blockIdx.x * 256 + threadIdx.x;
    out[i] = bias[i & 63];
}

// ---------------- Phase 1: Xh pack + coarse histogram (fused; bcnt pre-zeroed) ----------------
__global__ __launch_bounds__(1024) void prep_hist_kernel(const float* __restrict__ Xr,
                                                         const float* __restrict__ Xi,
                                                         const int* __restrict__ rows,
                                                         unsigned* __restrict__ Xh,
                                                         int* __restrict__ bcnt) {
    __shared__ int lh[NBUCK];
    const int tid = threadIdx.x;
    for (int t = tid; t < NBUCK; t += 1024) lh[t] = 0;
    __syncthreads();
    const int base = blockIdx.x * CHUNK_A;          // grid = NBLK_A = 782
#pragma unroll
    for (int h = 0; h < 2; ++h) {
        const int i = base + h * 1024 + tid;
        if (i < E_EDGES) {                          // 1.6M float4 items == 1.6M edges
            const float4 r = ((const float4*)Xr)[i];
            const float4 m = ((const float4*)Xi)[i];
            uint4 u;
            u.x = pack2(r.x, m.x);
            u.y = pack2(r.y, m.y);
            u.z = pack2(r.z, m.z);
            u.w = pack2(r.w, m.w);
            ((uint4*)Xh)[i] = u;
            atomicAdd(&lh[rows[i] >> 8], 1);
        }
    }
    __syncthreads();
    for (int t = tid; t < NBUCK; t += 1024)
        if (lh[t]) atomicAdd(&bcnt[t], lh[t]);
}

// ---------------- Scan of 391 bucket counts + W pack (single block) ----------------
// Bpack[(kc*4+nt)*64 + L] = 8 halves: W[kc*32 + (L>>4)*8 + j][nt*16 + (L&15)]
__global__ __launch_bounds__(512) void cscan_kernel(const int* __restrict__ bcnt,
                                                    int* __restrict__ cofs,
                                                    int* __restrict__ ccur,
                                                    const float* __restrict__ W,
                                                    h8f* __restrict__ Bpack) {
    __shared__ int s[512];
    const int t = threadIdx.x;
    int v = (t < NBUCK) ? bcnt[t] : 0;
    s[t] = v;
    __syncthreads();
    for (int off = 1; off < 512; off <<= 1) {
        int a = (t >= off) ? s[t - off] : 0;
        __syncthreads();
        s[t] += a;
        __syncthreads();
    }
    if (t < NBUCK) {
        cofs[t] = s[t] - v;
        ccur[t] = s[t] - v;
    }
    if (t == NBUCK - 1) cofs[NBUCK] = s[t];   // == E_EDGES

    for (int sidx = t; sidx < 24 * 64; sidx += 512) {
        const int L = sidx & 63;
        const int ntkc = sidx >> 6;
        const int nt = ntkc & 3;
        const int kc = ntkc >> 2;
        const int colb = nt * 16 + (L & 15);
        const int kbase = kc * 32 + ((L >> 4) << 3);
        h8f vv;
#pragma unroll
        for (int j = 0; j < 8; ++j) vv[j] = (_Float16)W[(kbase + j) * 64 + colb];
        Bpack[sidx] = vv;
    }
}

// ---------------- Phase A: LDS-staged radix partition, coalesced copy-out ----------------
// record (16 B): {col | (row&255)<<17, h2(lr0,li0), h2(lr1,li1), h2(lr2,li2)}
__global__ __launch_bounds__(1024) void partA_kernel(const int* __restrict__ rows,
                                                     const int* __restrict__ cols,
                                                     const float* __restrict__ Lr,
                                                     const float* __restrict__ Li,
                                                     int* __restrict__ ccur,
                                                     u32x4* __restrict__ temp) {
    __shared__ u32x4 sRec[CHUNK_A];       // 32,768 B, bucket-sorted records
    __shared__ int sDst[CHUNK_A];         //  8,192 B, global record index per record
    __shared__ int lh[NBUCK];
    __shared__ int lcur[NBUCK];
    __shared__ int gdel[NBUCK];           // global base - LDS base
    __shared__ int ss[512];
    const int tid = threadIdx.x;
    const int base = blockIdx.x * CHUNK_A;
    const int nedge = min(CHUNK_A, E_EDGES - base);

    for (int t = tid; t < NBUCK; t += 1024) lh[t] = 0;
    __syncthreads();
    for (int j = tid; j < nedge; j += 1024) atomicAdd(&lh[rows[base + j] >> 8], 1);
    __syncthreads();

    if (tid < 512) ss[tid] = (tid < NBUCK) ? lh[tid] : 0;
    __syncthreads();
    for (int off = 1; off < 512; off <<= 1) {
        int a = 0;
        if (tid < 512 && tid >= off) a = ss[tid - off];
        __syncthreads();
        if (tid < 512) ss[tid] += a;
        __syncthreads();
    }
    if (tid < NBUCK) {
        const int excl = ss[tid] - lh[tid];
        lcur[tid] = excl;
        const int gb = lh[tid] ? atomicAdd(&ccur[tid], lh[tid]) : 0;
        gdel[tid] = gb - excl;            // one global atomic per (block,bucket)
    }
    __syncthreads();

    for (int j = tid; j < nedge; j += 1024) {
        const int e = base + j;
        const int r = rows[e];
        const int bk = r >> 8;
        const int pos = atomicAdd(&lcur[bk], 1);
        u32x4 u;
        u.x = (unsigned)cols[e] | ((unsigned)(r & 255) << 17);
        u.y = pack2(Lr[e], Li[e]);
        u.z = pack2(Lr[E_EDGES + e], Li[E_EDGES + e]);
        u.w = pack2(Lr[2 * E_EDGES + e], Li[2 * E_EDGES + e]);
        sRec[pos] = u;
        sDst[pos] = gdel[bk] + pos;       // global record index
    }
    __syncthreads();

    // Coalesced copy-out: bucket-sorted LDS order -> piecewise-consecutive dests.
    for (int c = tid; c < nedge; c += 1024) temp[sDst[c]] = sRec[c];
}

// ---------------- Phase B: per-bucket fine sort (L2-local), 1024 threads ----------------
__global__ __launch_bounds__(1024) void partB_kernel(const int* __restrict__ cofs,
                                                     const u32x4* __restrict__ temp,
                                                     u32x4* __restrict__ payload,
                                                     int* __restrict__ rowst) {
    const int b = blockIdx.x;                 // grid = NBUCK
    const int t = threadIdx.x;
    const int start = cofs[b];
    const int endp = cofs[b + 1];
    __shared__ int lh[256];
    __shared__ int s[256];
    if (t < 256) lh[t] = 0;
    __syncthreads();
    for (int i = start + t; i < endp; i += 1024)
        atomicAdd(&lh[temp[i].x >> 17], 1);   // warms L2 for pass 2
    __syncthreads();
    int v = 0;
    if (t < 256) {
        v = lh[t];
        s[t] = v;
    }
    __syncthreads();
    for (int off = 1; off < 256; off <<= 1) {
        int a = (t >= off && t < 256) ? s[t - off] : 0;
        __syncthreads();
        if (t < 256) s[t] += a;
        __syncthreads();
    }
    if (t < 256) {
        const int excl = s[t] - v;
        rowst[b * 256 + t] = start + excl;
        lh[t] = excl;                          // becomes per-row cursor
    }
    if (b == NBUCK - 1 && t == 0) rowst[NBUCK * 256] = endp;   // guard
    __syncthreads();
    for (int i = start + t; i < endp; i += 1024) {
        u32x4 q = temp[i];
        const int rl = (int)(q.x >> 17);
        const int pos = start + atomicAdd(&lh[rl], 1);   // random within ~66 KB -> L2
        payload[pos] = q;
    }
}

// ---------------- FUSED main pass: 16 rows/block; 8-deep pipeline + MFMA epilogue ----------------
__global__ __launch_bounds__(256) void row6_kernel(const int* __restrict__ rowst,
                                                   const u32x4* __restrict__ payload,
                                                   const unsigned* __restrict__ Xh,
                                                   const h8f* __restrict__ Bpack,
                                                   const float* __restrict__ bias,
                                                   float* __restrict__ out) {
    __shared__ __half sY[2][16][200];          // 400 B row pitch: 2-way LDS alias only
    const int w = (int)threadIdx.x >> 6;       // wave id = 4 rows / nt quadrant
    const int lane = threadIdx.x & 63;
    const int band = blockIdx.x * 16;          // grid = 6250 exact

    for (int q = 0; q < 4; ++q) {
        const int ri = w * 4 + q;
        const int r = __builtin_amdgcn_readfirstlane(band + ri);
        const int start = rowst[r];
        const int end = rowst[r + 1];
        const int n = end - start;

        float aR0 = 0.f, aI0 = 0.f, aR1 = 0.f, aI1 = 0.f, aR2 = 0.f, aI2 = 0.f;

        auto gx = [&](unsigned cw) -> unsigned {
            return Xh[(size_t)(cw & COLMASK) * 64 + lane];
        };
        auto accum = [&](const u32x4& qq, unsigned xv) {
            aR0 = fdot2h(qq.y ^ 0x80000000u, xv, aR0);
            aI0 = fdot2h(rot16(qq.y), xv, aI0);
            aR1 = fdot2h(qq.z ^ 0x80000000u, xv, aR1);
            aI1 = fdot2h(rot16(qq.z), xv, aI1);
            aR2 = fdot2h(qq.w ^ 0x80000000u, xv, aR2);
            aI2 = fdot2h(rot16(qq.w), xv, aI2);
        };

        if (n >= 12) {
            int p = start;
            u32x4 P0 = payload[p], P1 = payload[p + 1], P2 = payload[p + 2],
                  P3 = payload[p + 3], P4 = payload[p + 4], P5 = payload[p + 5],
                  P6 = payload[p + 6], P7 = payload[p + 7];
            unsigned x0 = gx(P0.x), x1 = gx(P1.x), x2 = gx(P2.x), x3 = gx(P3.x);
            unsigned x4 = gx(P4.x), x5 = gx(P5.x), x6 = gx(P6.x), x7 = gx(P7.x);

            for (; p + 11 < end; p += 4) {
                u32x4 Q0 = payload[p + 8], Q1 = payload[p + 9];
                u32x4 Q2 = payload[p + 10], Q3 = payload[p + 11];
                accum(P0, x0);
                accum(P1, x1);
                accum(P2, x2);
                accum(P3, x3);
                P0 = P4; P1 = P5; P2 = P6; P3 = P7;
                x0 = x4; x1 = x5; x2 = x6; x3 = x7;
                P4 = Q0; P5 = Q1; P6 = Q2; P7 = Q3;
                x4 = gx(P4.x);
                x5 = gx(P5.x);
                x6 = gx(P6.x);
                x7 = gx(P7.x);
            }
            // rem = end - p in [8, 11]; x0..x7 all in flight for P0..P7
            accum(P0, x0);
            accum(P1, x1);
            accum(P2, x2);
            accum(P3, x3);
            accum(P4, x4);
            accum(P5, x5);
            accum(P6, x6);
            accum(P7, x7);
            for (p += 8; p < end; ++p) {
                u32x4 qq = payload[p];
                unsigned xv = gx(qq.x);
                accum(qq, xv);
            }
        } else {
            for (int p = start; p < end; ++p) {
                u32x4 qq = payload[p];
                unsigned xv = gx(qq.x);
                accum(qq, xv);
            }
        }

        sY[0][ri][lane] = __float2half(aR0);
        sY[0][ri][64 + lane] = __float2half(aR1);
        sY[0][ri][128 + lane] = __float2half(aR2);
        sY[1][ri][lane] = __float2half(aI0);
        sY[1][ri][64 + lane] = __float2half(aI1);
        sY[1][ri][128 + lane] = __float2half(aI2);
    }
    __syncthreads();

    // MFMA epilogue: wave w = column quadrant nt = w.
    const int nt = w;
    const int m = lane & 15;
    const int ko = (lane >> 4) << 3;
    f32x4 accR = (f32x4){0.f, 0.f, 0.f, 0.f};
    f32x4 accI = (f32x4){0.f, 0.f, 0.f, 0.f};
#pragma unroll
    for (int kc = 0; kc < 6; ++kc) {
        h8f bf = Bpack[(kc * 4 + nt) * 64 + lane];                    // L3-hot, 16 B/lane
        h8f aR = *(const h8f*)&sY[0][m][kc * 32 + ko];
        h8f aI = *(const h8f*)&sY[1][m][kc * 32 + ko];
        accR = __builtin_amdgcn_mfma_f32_16x16x32_f16(aR, bf, accR, 0, 0, 0);
        accI = __builtin_amdgcn_mfma_f32_16x16x32_f16(aI, bf, accI, 0, 0, 0);
    }
    const int colw = lane & 15;
    const int rbase = (lane >> 4) << 2;
    const float b = bias[nt * 16 + colw];
#pragma unroll
    for (int rr = 0; rr < 4; ++rr) {
        const int row = band + rbase + rr;
        __builtin_nontemporal_store(accR[rr] + b,
                                    &out[(size_t)row * 64 + nt * 16 + colw]);
        __builtin_nontemporal_store(accI[rr] + b,
                                    &out[(size_t)(N_NODES + row) * 64 + nt * 16 + colw]);
    }
}

// ================= Fallback kernels (small-ws paths) =================
template <int NK>
__global__ __launch_bounds__(256) void xw_kernel(const float* __restrict__ Xr,
                                                 const float* __restrict__ Xi,
                                                 const float* __restrict__ W,
                                                 __half2* __restrict__ XWh) {
    __shared__ float sW[NK][64][64];
    __shared__ float4 sX4[2][32][16];
    const int tid = threadIdx.x;

    float4* swf = (float4*)&sW[0][0][0];
    const float4* gW = (const float4*)W;
    for (int i = tid; i < NK * 1024; i += 256) swf[i] = gW[i];

    const int rowbase = blockIdx.x * 32;
    float4* sxf = (float4*)sX4;
    const float4* gXr = (const float4*)(Xr + (size_t)rowbase * CH);
    const float4* gXi = (const float4*)(Xi + (size_t)rowbase * CH);
    for (int i = tid; i < 512; i += 256) {
        sxf[i] = gXr[i];
        sxf[512 + i] = gXi[i];
    }
    __syncthreads();

    const int col = tid & 63;
    const int rg = tid >> 6;

    float acc[8][2 * NK];
#pragma unroll
    for (int i = 0; i < 8; ++i)
#pragma unroll
        for (int c2 = 0; c2 < 2 * NK; ++c2) acc[i][c2] = 0.0f;

#pragma unroll 2
    for (int j4 = 0; j4 < 16; ++j4) {
        float w[NK][4];
#pragma unroll
        for (int k = 0; k < NK; ++k)
#pragma unroll
            for (int jj = 0; jj < 4; ++jj) w[k][jj] = sW[k][j4 * 4 + jj][col];
#pragma unroll
        for (int i = 0; i < 8; ++i) {
            float4 xr = sX4[0][rg * 8 + i][j4];
            float4 xi = sX4[1][rg * 8 + i][j4];
            const float xra[4] = {xr.x, xr.y, xr.z, xr.w};
            const float xia[4] = {xi.x, xi.y, xi.z, xi.w};
#pragma unroll
            for (int jj = 0; jj < 4; ++jj)
#pragma unroll
                for (int k = 0; k < NK; ++k) {
                    acc[i][2 * k] += xra[jj] * w[k][jj];
                    acc[i][2 * k + 1] += xia[jj] * w[k][jj];
                }
        }
    }

#pragma unroll
    for (int i = 0; i < 8; ++i) {
        __half2* dst = XWh + (size_t)(rowbase + rg * 8 + i) * (NK * 64);
#pragma unroll
        for (int k = 0; k < NK; ++k)
            dst[k * 64 + col] = __floats2half2_rn(acc[i][2 * k], acc[i][2 * k + 1]);
    }
}

template <int NK>
__global__ __launch_bounds__(256) void edge_kernel(const int* __restrict__ rows,
                                                   const int* __restrict__ cols,
                                                   const float* __restrict__ Lr,
                                                   const float* __restrict__ Li,
                                                   const __half2* __restrict__ XWh,
                                                   float* __restrict__ out) {
    const int gid = blockIdx.x * 256 + threadIdx.x;
    const int e = gid >> 6;
    const int lane = gid & 63;
    if (e >= E_EDGES) return;

    const int row = rows[e];
    const int colN = cols[e];
    const __half2* xw = XWh + (size_t)colN * (NK * 64);

    float rc = 0.0f, ic = 0.0f;
#pragma unroll
    for (int k = 0; k < NK; ++k) {
        const float lr = Lr[(size_t)k * E_EDGES + e];
        const float li = Li[(size_t)k * E_EDGES + e];
        float2 v = __half22float2(xw[k * 64 + lane]);
        rc += lr * v.x - li * v.y;
        ic += li * v.x + lr * v.y;
    }
    unsafeAtomicAdd(out + (size_t)row * 64 + lane, rc);
    unsafeAtomicAdd(out + ((size_t)N_NODES + row) * 64 + lane, ic);
}

extern "C" void kernel_launch(void* const* d_in, const int* in_sizes, int n_in,
                              void* d_out, int out_size, void* d_ws, size_t ws_size,
                              hipStream_t stream) {
    const float* Xr = (const float*)d_in[0];
    const float* Xi = (const float*)d_in[1];
    const int* ei = (const int*)d_in[2];
    const float* Lr = (const float*)d_in[3];
    const float* Li = (const float*)d_in[4];
    const float* W = (const float*)d_in[5];
    const float* bias = (const float*)d_in[6];
    float* out = (float*)d_out;

    const int* rows = ei;
    const int* cols = ei + E_EDGES;

    char* wsb = (char*)d_ws;
    const int edge_grid = (int)((size_t)E_EDGES * 64 / 256);      // 400000
    const int gemm_grid = N_NODES / 32;                           // 3125

    // Main-path ws layout (16 B records)
    unsigned* Xh = (unsigned*)wsb;                                //  25,600,000 B
    unsigned* payload = (unsigned*)(wsb + 25600000);              //  25,600,000 B (16 B/edge)
    u32x4* temp = (u32x4*)(wsb + 51200000);                       //  25,600,000 B
    int* rowst = (int*)(wsb + 76800000);                          //     404,480 B (NP+1 used)
    int* bcnt = (int*)(wsb + 77204480);                           //       1,600 B
    int* cofs = (int*)(wsb + 77206080);                           //       1,600 B
    int* ccur = (int*)(wsb + 77207680);                           //       1,600 B
    h8f* Bpack = (h8f*)(wsb + 77209280);                          //      24,576 B
    const size_t need_new = 77233856;

    if (ws_size >= need_new) {
        hipMemsetAsync(bcnt, 0, NBUCK * sizeof(int), stream);
        prep_hist_kernel<<<NBLK_A, 1024, 0, stream>>>(Xr, Xi, rows, Xh, bcnt);
        cscan_kernel<<<1, 512, 0, stream>>>(bcnt, cofs, ccur, W, Bpack);
        partA_kernel<<<NBLK_A, 1024, 0, stream>>>(rows, cols, Lr, Li, ccur, temp);
        partB_kernel<<<NBUCK, 1024, 0, stream>>>(cofs, temp, (u32x4*)payload, rowst);
        row6_kernel<<<N_NODES / 16, 256, 0, stream>>>(rowst, (const u32x4*)payload, Xh,
                                                      Bpack, bias, out);
        return;
    }

    // Fallback ws layout (atomic edge scatter over XWh table)
    __half2* XWh = (__half2*)wsb;                                 //  76,800,000 B
    const size_t need_onepass = 76800000;

    if (ws_size >= need_onepass) {
        init_out_kernel<<<2 * N_NODES * CH / 256, 256, 0, stream>>>(bias, out);
        xw_kernel<3><<<gemm_grid, 256, 0, stream>>>(Xr, Xi, W, XWh);
        edge_kernel<3><<<edge_grid, 256, 0, stream>>>(rows, cols, Lr, Li, XWh, out);
    } else {
        init_out_kernel<<<2 * N_NODES * CH / 256, 256, 0, stream>>>(bias, out);
        for (int k = 0; k < 3; ++k) {
            xw_kernel<1><<<gemm_grid, 256, 0, stream>>>(Xr, Xi, W + (size_t)k * 4096, XWh);
            edge_kernel<1><<<edge_grid, 256, 0, stream>>>(rows, cols,
                                                          Lr + (size_t)k * E_EDGES,
                                                          Li + (size_t)k * E_EDGES, XWh, out);
        }
    }
}

// Round 20
// 156.113 us; speedup vs baseline: 1.3929x; 1.0032x over previous
//
#include <hip/hip_runtime.h>
#include <hip/hip_fp16.h>

// SDConv on MI355X.
// Reference: out = sum_k spmm(L_k, X) @ W_k + bias  (complex).
// Structure: apply W AFTER the spmm (k-expansion lives in the L domain), so the
// gather table is just X: 25.6 MB fp16 -> L2/L3-resident.
//   1. prep_hist_kernel: Xh[node][ch] = half2(Xr, Xi) AND per-block coarse bucket
//      histograms (saved to bhist for reuse; global sum to bcnt).
//   2. Hierarchical CSR build (random-64B-line writeback amplification R9/R10/R12;
//      occupancy R13/R15; NT-load lesson R16; 16 B records R18; R20: bhist reuse
//      kills partA's duplicate histogram pass + global atomics):
//      cscan(+Wpack) -> colscan (per-(block,bucket) offsets) ->
//      partA (LDS radix partition, deterministic, coalesced copy-out) ->
//      partB (per-bucket fine sort, L2-local, 1024-thr; emits rowst).
//   3. row6_kernel (FUSED row pass + output GEMM): block = 16 rows; 4 waves x 4
//      rows; 8-slot scalar payload pipeline with 8 X-gathers in flight; (lr,-li)/
//      (li,lr) derived via s_xor/rot16; 6 dot2/edge; Y in LDS (400 B pitch);
//      MFMA per 16-col quadrant; NT-stores out + bias.

constexpr int N_NODES = 100000;
constexpr int E_EDGES = 1600000;
constexpr int CH = 64;
constexpr int NP = 100096;          // N padded to multiple of 256
constexpr int NBUCK = NP / 256;     // 391 coarse buckets (256 rows each)
constexpr int CHUNK_A = 2048;       // edges per partition block
constexpr int NBLK_A = (E_EDGES + CHUNK_A - 1) / CHUNK_A;   // 782
constexpr unsigned COLMASK = 0x1FFFFu;

typedef unsigned u32x4 __attribute__((ext_vector_type(4)));
typedef _Float16 h2f __attribute__((ext_vector_type(2)));
typedef _Float16 h8f __attribute__((ext_vector_type(8)));
typedef float f32x4 __attribute__((ext_vector_type(4)));

// f32 += dot(half2, half2) with f32 accumulation (v_dot2_f32_f16).
__device__ __forceinline__ float fdot2h(unsigned a, unsigned b, float c) {
#if __has_builtin(__builtin_amdgcn_fdot2)
    return __builtin_amdgcn_fdot2(__builtin_bit_cast(h2f, a),
                                  __builtin_bit_cast(h2f, b), c, false);
#else
    float2 af = __half22float2(__builtin_bit_cast(__half2, a));
    float2 bf = __half22float2(__builtin_bit_cast(__half2, b));
    return c + af.x * bf.x + af.y * bf.y;
#endif
}

__device__ __forceinline__ unsigned pack2(float a, float b) {
    return __builtin_bit_cast(unsigned, __floats2half2_rn(a, b));
}

__device__ __forceinline__ unsigned rot16(unsigned u) {
    return (u >> 16) | (u << 16);
}

__global__ __launch_bounds__(256) void init_out_kernel(const float* __restrict__ bias,
                                                       float* __restrict__ out) {
    int i = blockIdx.x * 256 + threadIdx.x;
    out[i] = bias[i & 63];
}

// ---------------- Phase 1: Xh pack + per-block histograms (bcnt pre-zeroed) ----------------
__global__ __launch_bounds__(1024) void prep_hist_kernel(const float* __restrict__ Xr,
                                                         const float* __restrict__ Xi,
                                                         const int* __restrict__ rows,
                                                         unsigned* __restrict__ Xh,
                                                         int* __restrict__ bcnt,
                                                         int* __restrict__ bhist) {
    __shared__ int lh[NBUCK];
    const int tid = threadIdx.x;
    for (int t = tid; t < NBUCK; t += 1024) lh[t] = 0;
    __syncthreads();
    const int base = blockIdx.x * CHUNK_A;          // grid = NBLK_A = 782
#pragma unroll
    for (int h = 0; h < 2; ++h) {
        const int i = base + h * 1024 + tid;
        if (i < E_EDGES) {                          // 1.6M float4 items == 1.6M edges
            const float4 r = ((const float4*)Xr)[i];
            const float4 m = ((const float4*)Xi)[i];
            uint4 u;
            u.x = pack2(r.x, m.x);
            u.y = pack2(r.y, m.y);
            u.z = pack2(r.z, m.z);
            u.w = pack2(r.w, m.w);
            ((uint4*)Xh)[i] = u;
            atomicAdd(&lh[rows[i] >> 8], 1);
        }
    }
    __syncthreads();
    for (int t = tid; t < NBUCK; t += 1024) {
        const int c = lh[t];
        bhist[(size_t)blockIdx.x * NBUCK + t] = c;   // save for colscan/partA
        if (c) atomicAdd(&bcnt[t], c);
    }
}

// ---------------- Scan of 391 bucket counts + W pack (single block) ----------------
// Bpack[(kc*4+nt)*64 + L] = 8 halves: W[kc*32 + (L>>4)*8 + j][nt*16 + (L&15)]
__global__ __launch_bounds__(512) void cscan_kernel(const int* __restrict__ bcnt,
                                                    int* __restrict__ cofs,
                                                    const float* __restrict__ W,
                                                    h8f* __restrict__ Bpack) {
    __shared__ int s[512];
    const int t = threadIdx.x;
    int v = (t < NBUCK) ? bcnt[t] : 0;
    s[t] = v;
    __syncthreads();
    for (int off = 1; off < 512; off <<= 1) {
        int a = (t >= off) ? s[t - off] : 0;
        __syncthreads();
        s[t] += a;
        __syncthreads();
    }
    if (t < NBUCK) cofs[t] = s[t] - v;
    if (t == NBUCK - 1) cofs[NBUCK] = s[t];   // == E_EDGES

    for (int sidx = t; sidx < 24 * 64; sidx += 512) {
        const int L = sidx & 63;
        const int ntkc = sidx >> 6;
        const int nt = ntkc & 3;
        const int kc = ntkc >> 2;
        const int colb = nt * 16 + (L & 15);
        const int kbase = kc * 32 + ((L >> 4) << 3);
        h8f vv;
#pragma unroll
        for (int j = 0; j < 8; ++j) vv[j] = (_Float16)W[(kbase + j) * 64 + colb];
        Bpack[sidx] = vv;
    }
}

// ---------------- Column scan: bofs[blk][b] = cofs[b] + sum_{blk'<blk} bhist[blk'][b] ----------------
__global__ __launch_bounds__(256) void colscan_kernel(const int* __restrict__ cofs,
                                                      const int* __restrict__ bhist,
                                                      int* __restrict__ bofs) {
    const int b = blockIdx.x;                 // grid = NBUCK
    const int t = threadIdx.x;
    __shared__ int s[256];
    __shared__ int carry;
    if (t == 0) carry = cofs[b];
    __syncthreads();
    for (int base = 0; base < NBLK_A; base += 256) {
        const int idx = base + t;
        int v = (idx < NBLK_A) ? bhist[(size_t)idx * NBUCK + b] : 0;
        s[t] = v;
        __syncthreads();
        for (int off = 1; off < 256; off <<= 1) {
            int a = (t >= off) ? s[t - off] : 0;
            __syncthreads();
            s[t] += a;
            __syncthreads();
        }
        if (idx < NBLK_A) bofs[(size_t)idx * NBUCK + b] = carry + s[t] - v;
        __syncthreads();
        if (t == 255) carry += s[255];
        __syncthreads();
    }
}

// ---------------- Phase A: LDS radix partition (deterministic), coalesced copy-out ----------------
// record (16 B): {col | (row&255)<<17, h2(lr0,li0), h2(lr1,li1), h2(lr2,li2)}
__global__ __launch_bounds__(1024) void partA_kernel(const int* __restrict__ rows,
                                                     const int* __restrict__ cols,
                                                     const float* __restrict__ Lr,
                                                     const float* __restrict__ Li,
                                                     const int* __restrict__ bhist,
                                                     const int* __restrict__ bofs,
                                                     u32x4* __restrict__ temp) {
    __shared__ u32x4 sRec[CHUNK_A];       // 32,768 B, bucket-sorted records
    __shared__ int sDst[CHUNK_A];         //  8,192 B, global record index per record
    __shared__ int lh[NBUCK];
    __shared__ int lcur[NBUCK];
    __shared__ int gdel[NBUCK];           // global base - LDS base
    __shared__ int ss[512];
    const int tid = threadIdx.x;
    const int base = blockIdx.x * CHUNK_A;
    const int nedge = min(CHUNK_A, E_EDGES - base);

    if (tid < NBUCK) lh[tid] = bhist[(size_t)blockIdx.x * NBUCK + tid];
    __syncthreads();
    if (tid < 512) ss[tid] = (tid < NBUCK) ? lh[tid] : 0;
    __syncthreads();
    for (int off = 1; off < 512; off <<= 1) {
        int a = 0;
        if (tid < 512 && tid >= off) a = ss[tid - off];
        __syncthreads();
        if (tid < 512) ss[tid] += a;
        __syncthreads();
    }
    if (tid < NBUCK) {
        const int excl = ss[tid] - lh[tid];
        lcur[tid] = excl;
        gdel[tid] = bofs[(size_t)blockIdx.x * NBUCK + tid] - excl;
    }
    __syncthreads();

    for (int j = tid; j < nedge; j += 1024) {
        const int e = base + j;
        const int r = rows[e];
        const int bk = r >> 8;
        const int pos = atomicAdd(&lcur[bk], 1);
        u32x4 u;
        u.x = (unsigned)cols[e] | ((unsigned)(r & 255) << 17);
        u.y = pack2(Lr[e], Li[e]);
        u.z = pack2(Lr[E_EDGES + e], Li[E_EDGES + e]);
        u.w = pack2(Lr[2 * E_EDGES + e], Li[2 * E_EDGES + e]);
        sRec[pos] = u;
        sDst[pos] = gdel[bk] + pos;       // global record index
    }
    __syncthreads();

    // Coalesced copy-out: bucket-sorted LDS order -> piecewise-consecutive dests.
    for (int c = tid; c < nedge; c += 1024) temp[sDst[c]] = sRec[c];
}

// ---------------- Phase B: per-bucket fine sort (L2-local), 1024 threads ----------------
__global__ __launch_bounds__(1024) void partB_kernel(const int* __restrict__ cofs,
                                                     const u32x4* __restrict__ temp,
                                                     u32x4* __restrict__ payload,
                                                     int* __restrict__ rowst) {
    const int b = blockIdx.x;                 // grid = NBUCK
    const int t = threadIdx.x;
    const int start = cofs[b];
    const int endp = cofs[b + 1];
    __shared__ int lh[256];
    __shared__ int s[256];
    if (t < 256) lh[t] = 0;
    __syncthreads();
    for (int i = start + t; i < endp; i += 1024)
        atomicAdd(&lh[temp[i].x >> 17], 1);   // warms L2 for pass 2
    __syncthreads();
    int v = 0;
    if (t < 256) {
        v = lh[t];
        s[t] = v;
    }
    __syncthreads();
    for (int off = 1; off < 256; off <<= 1) {
        int a = (t >= off && t < 256) ? s[t - off] : 0;
        __syncthreads();
        if (t < 256) s[t] += a;
        __syncthreads();
    }
    if (t < 256) {
        const int excl = s[t] - v;
        rowst[b * 256 + t] = start + excl;
        lh[t] = excl;                          // becomes per-row cursor
    }
    if (b == NBUCK - 1 && t == 0) rowst[NBUCK * 256] = endp;   // guard
    __syncthreads();
    for (int i = start + t; i < endp; i += 1024) {
        u32x4 q = temp[i];
        const int rl = (int)(q.x >> 17);
        const int pos = start + atomicAdd(&lh[rl], 1);   // random within ~66 KB -> L2
        payload[pos] = q;
    }
}

// ---------------- FUSED main pass: 16 rows/block; 8-deep pipeline + MFMA epilogue ----------------
__global__ __launch_bounds__(256) void row6_kernel(const int* __restrict__ rowst,
                                                   const u32x4* __restrict__ payload,
                                                   const unsigned* __restrict__ Xh,
                                                   const h8f* __restrict__ Bpack,
                                                   const float* __restrict__ bias,
                                                   float* __restrict__ out) {
    __shared__ __half sY[2][16][200];          // 400 B row pitch: 2-way LDS alias only
    const int w = (int)threadIdx.x >> 6;       // wave id = 4 rows / nt quadrant
    const int lane = threadIdx.x & 63;
    const int band = blockIdx.x * 16;          // grid = 6250 exact

    for (int q = 0; q < 4; ++q) {
        const int ri = w * 4 + q;
        const int r = __builtin_amdgcn_readfirstlane(band + ri);
        const int start = rowst[r];
        const int end = rowst[r + 1];
        const int n = end - start;

        float aR0 = 0.f, aI0 = 0.f, aR1 = 0.f, aI1 = 0.f, aR2 = 0.f, aI2 = 0.f;

        auto gx = [&](unsigned cw) -> unsigned {
            return Xh[(size_t)(cw & COLMASK) * 64 + lane];
        };
        auto accum = [&](const u32x4& qq, unsigned xv) {
            aR0 = fdot2h(qq.y ^ 0x80000000u, xv, aR0);
            aI0 = fdot2h(rot16(qq.y), xv, aI0);
            aR1 = fdot2h(qq.z ^ 0x80000000u, xv, aR1);
            aI1 = fdot2h(rot16(qq.z), xv, aI1);
            aR2 = fdot2h(qq.w ^ 0x80000000u, xv, aR2);
            aI2 = fdot2h(rot16(qq.w), xv, aI2);
        };

        if (n >= 12) {
            int p = start;
            u32x4 P0 = payload[p], P1 = payload[p + 1], P2 = payload[p + 2],
                  P3 = payload[p + 3], P4 = payload[p + 4], P5 = payload[p + 5],
                  P6 = payload[p + 6], P7 = payload[p + 7];
            unsigned x0 = gx(P0.x), x1 = gx(P1.x), x2 = gx(P2.x), x3 = gx(P3.x);
            unsigned x4 = gx(P4.x), x5 = gx(P5.x), x6 = gx(P6.x), x7 = gx(P7.x);

            for (; p + 11 < end; p += 4) {
                u32x4 Q0 = payload[p + 8], Q1 = payload[p + 9];
                u32x4 Q2 = payload[p + 10], Q3 = payload[p + 11];
                accum(P0, x0);
                accum(P1, x1);
                accum(P2, x2);
                accum(P3, x3);
                P0 = P4; P1 = P5; P2 = P6; P3 = P7;
                x0 = x4; x1 = x5; x2 = x6; x3 = x7;
                P4 = Q0; P5 = Q1; P6 = Q2; P7 = Q3;
                x4 = gx(P4.x);
                x5 = gx(P5.x);
                x6 = gx(P6.x);
                x7 = gx(P7.x);
            }
            accum(P0, x0);
            accum(P1, x1);
            accum(P2, x2);
            accum(P3, x3);
            accum(P4, x4);
            accum(P5, x5);
            accum(P6, x6);
            accum(P7, x7);
            for (p += 8; p < end; ++p) {
                u32x4 qq = payload[p];
                unsigned xv = gx(qq.x);
                accum(qq, xv);
            }
        } else {
            for (int p = start; p < end; ++p) {
                u32x4 qq = payload[p];
                unsigned xv = gx(qq.x);
                accum(qq, xv);
            }
        }

        sY[0][ri][lane] = __float2half(aR0);
        sY[0][ri][64 + lane] = __float2half(aR1);
        sY[0][ri][128 + lane] = __float2half(aR2);
        sY[1][ri][lane] = __float2half(aI0);
        sY[1][ri][64 + lane] = __float2half(aI1);
        sY[1][ri][128 + lane] = __float2half(aI2);
    }
    __syncthreads();

    // MFMA epilogue: wave w = column quadrant nt = w.
    const int nt = w;
    const int m = lane & 15;
    const int ko = (lane >> 4) << 3;
    f32x4 accR = (f32x4){0.f, 0.f, 0.f, 0.f};
    f32x4 accI = (f32x4){0.f, 0.f, 0.f, 0.f};
#pragma unroll
    for (int kc = 0; kc < 6; ++kc) {
        h8f bf = Bpack[(kc * 4 + nt) * 64 + lane];                    // L3-hot, 16 B/lane
        h8f aR = *(const h8f*)&sY[0][m][kc * 32 + ko];
        h8f aI = *(const h8f*)&sY[1][m][kc * 32 + ko];
        accR = __builtin_amdgcn_mfma_f32_16x16x32_f16(aR, bf, accR, 0, 0, 0);
        accI = __builtin_amdgcn_mfma_f32_16x16x32_f16(aI, bf, accI, 0, 0, 0);
    }
    const int colw = lane & 15;
    const int rbase = (lane >> 4) << 2;
    const float b = bias[nt * 16 + colw];
#pragma unroll
    for (int rr = 0; rr < 4; ++rr) {
        const int row = band + rbase + rr;
        __builtin_nontemporal_store(accR[rr] + b,
                                    &out[(size_t)row * 64 + nt * 16 + colw]);
        __builtin_nontemporal_store(accI[rr] + b,
                                    &out[(size_t)(N_NODES + row) * 64 + nt * 16 + colw]);
    }
}

// ================= Fallback kernels (small-ws paths) =================
template <int NK>
__global__ __launch_bounds__(256) void xw_kernel(const float* __restrict__ Xr,
                                                 const float* __restrict__ Xi,
                                                 const float* __restrict__ W,
                                                 __half2* __restrict__ XWh) {
    __shared__ float sW[NK][64][64];
    __shared__ float4 sX4[2][32][16];
    const int tid = threadIdx.x;

    float4* swf = (float4*)&sW[0][0][0];
    const float4* gW = (const float4*)W;
    for (int i = tid; i < NK * 1024; i += 256) swf[i] = gW[i];

    const int rowbase = blockIdx.x * 32;
    float4* sxf = (float4*)sX4;
    const float4* gXr = (const float4*)(Xr + (size_t)rowbase * CH);
    const float4* gXi = (const float4*)(Xi + (size_t)rowbase * CH);
    for (int i = tid; i < 512; i += 256) {
        sxf[i] = gXr[i];
        sxf[512 + i] = gXi[i];
    }
    __syncthreads();

    const int col = tid & 63;
    const int rg = tid >> 6;

    float acc[8][2 * NK];
#pragma unroll
    for (int i = 0; i < 8; ++i)
#pragma unroll
        for (int c2 = 0; c2 < 2 * NK; ++c2) acc[i][c2] = 0.0f;

#pragma unroll 2
    for (int j4 = 0; j4 < 16; ++j4) {
        float w[NK][4];
#pragma unroll
        for (int k = 0; k < NK; ++k)
#pragma unroll
            for (int jj = 0; jj < 4; ++jj) w[k][jj] = sW[k][j4 * 4 + jj][col];
#pragma unroll
        for (int i = 0; i < 8; ++i) {
            float4 xr = sX4[0][rg * 8 + i][j4];
            float4 xi = sX4[1][rg * 8 + i][j4];
            const float xra[4] = {xr.x, xr.y, xr.z, xr.w};
            const float xia[4] = {xi.x, xi.y, xi.z, xi.w};
#pragma unroll
            for (int jj = 0; jj < 4; ++jj)
#pragma unroll
                for (int k = 0; k < NK; ++k) {
                    acc[i][2 * k] += xra[jj] * w[k][jj];
                    acc[i][2 * k + 1] += xia[jj] * w[k][jj];
                }
        }
    }

#pragma unroll
    for (int i = 0; i < 8; ++i) {
        __half2* dst = XWh + (size_t)(rowbase + rg * 8 + i) * (NK * 64);
#pragma unroll
        for (int k = 0; k < NK; ++k)
            dst[k * 64 + col] = __floats2half2_rn(acc[i][2 * k], acc[i][2 * k + 1]);
    }
}

template <int NK>
__global__ __launch_bounds__(256) void edge_kernel(const int* __restrict__ rows,
                                                   const int* __restrict__ cols,
                                                   const float* __restrict__ Lr,
                                                   const float* __restrict__ Li,
                                                   const __half2* __restrict__ XWh,
                                                   float* __restrict__ out) {
    const int gid = blockIdx.x * 256 + threadIdx.x;
    const int e = gid >> 6;
    const int lane = gid & 63;
    if (e >= E_EDGES) return;

    const int row = rows[e];
    const int colN = cols[e];
    const __half2* xw = XWh + (size_t)colN * (NK * 64);

    float rc = 0.0f, ic = 0.0f;
#pragma unroll
    for (int k = 0; k < NK; ++k) {
        const float lr = Lr[(size_t)k * E_EDGES + e];
        const float li = Li[(size_t)k * E_EDGES + e];
        float2 v = __half22float2(xw[k * 64 + lane]);
        rc += lr * v.x - li * v.y;
        ic += li * v.x + lr * v.y;
    }
    unsafeAtomicAdd(out + (size_t)row * 64 + lane, rc);
    unsafeAtomicAdd(out + ((size_t)N_NODES + row) * 64 + lane, ic);
}

extern "C" void kernel_launch(void* const* d_in, const int* in_sizes, int n_in,
                              void* d_out, int out_size, void* d_ws, size_t ws_size,
                              hipStream_t stream) {
    const float* Xr = (const float*)d_in[0];
    const float* Xi = (const float*)d_in[1];
    const int* ei = (const int*)d_in[2];
    const float* Lr = (const float*)d_in[3];
    const float* Li = (const float*)d_in[4];
    const float* W = (const float*)d_in[5];
    const float* bias = (const float*)d_in[6];
    float* out = (float*)d_out;

    const int* rows = ei;
    const int* cols = ei + E_EDGES;

    char* wsb = (char*)d_ws;
    const int edge_grid = (int)((size_t)E_EDGES * 64 / 256);      // 400000
    const int gemm_grid = N_NODES / 32;                           // 3125

    // Main-path ws layout (16 B records)
    unsigned* Xh = (unsigned*)wsb;                                //  25,600,000 B
    unsigned* payload = (unsigned*)(wsb + 25600000);              //  25,600,000 B (16 B/edge)
    u32x4* temp = (u32x4*)(wsb + 51200000);                       //  25,600,000 B
    int* rowst = (int*)(wsb + 76800000);                          //     404,480 B (NP+1 used)
    int* bcnt = (int*)(wsb + 77204480);                           //       1,600 B
    int* cofs = (int*)(wsb + 77206080);                           //       1,600 B
    h8f* Bpack = (h8f*)(wsb + 77207680);                          //      24,576 B
    int* bhist = (int*)(wsb + 77232256);                          //   1,223,168 B
    int* bofs = (int*)(wsb + 78455424);                           //   1,223,168 B
    const size_t need_new = 79678592;

    if (ws_size >= need_new) {
        hipMemsetAsync(bcnt, 0, NBUCK * sizeof(int), stream);
        prep_hist_kernel<<<NBLK_A, 1024, 0, stream>>>(Xr, Xi, rows, Xh, bcnt, bhist);
        cscan_kernel<<<1, 512, 0, stream>>>(bcnt, cofs, W, Bpack);
        colscan_kernel<<<NBUCK, 256, 0, stream>>>(cofs, bhist, bofs);
        partA_kernel<<<NBLK_A, 1024, 0, stream>>>(rows, cols, Lr, Li, bhist, bofs, temp);
        partB_kernel<<<NBUCK, 1024, 0, stream>>>(cofs, temp, (u32x4*)payload, rowst);
        row6_kernel<<<N_NODES / 16, 256, 0, stream>>>(rowst, (const u32x4*)payload, Xh,
                                                      Bpack, bias, out);
        return;
    }

    // Fallback ws layout (atomic edge scatter over XWh table)
    __half2* XWh = (__half2*)wsb;                                 //  76,800,000 B
    const size_t need_onepass = 76800000;

    if (ws_size >= need_onepass) {
        init_out_kernel<<<2 * N_NODES * CH / 256, 256, 0, stream>>>(bias, out);
        xw_kernel<3><<<gemm_grid, 256, 0, stream>>>(Xr, Xi, W, XWh);
        edge_kernel<3><<<edge_grid, 256, 0, stream>>>(rows, cols, Lr, Li, XWh, out);
    } else {
        init_out_kernel<<<2 * N_NODES * CH / 256, 256, 0, stream>>>(bias, out);
        for (int k = 0; k < 3; ++k) {
            xw_kernel<1><<<gemm_grid, 256, 0, stream>>>(Xr, Xi, W + (size_t)k * 4096, XWh);
            edge_kernel<1><<<edge_grid, 256, 0, stream>>>(rows, cols,
                                                          Lr + (size_t)k * E_EDGES,
                                                          Li + (size_t)k * E_EDGES, XWh, out);
        }
    }
}

// Round 21
// 155.697 us; speedup vs baseline: 1.3966x; 1.0027x over previous
//
#include <hip/hip_runtime.h>
#include <hip/hip_fp16.h>

// SDConv on MI355X.
// Reference: out = sum_k spmm(L_k, X) @ W_k + bias  (complex).
// Structure: apply W AFTER the spmm (k-expansion lives in the L domain), so the
// gather table is just X: 25.6 MB fp16 -> L2/L3-resident.
//   1. prep_hist_kernel: Xh[node][ch] = half2(Xr, Xi) AND per-block coarse bucket
//      histograms (saved to bhist; global sum to bcnt).
//   2. Hierarchical CSR build (random-64B-line writeback amplification R9/R10/R12;
//      occupancy R13/R15; NT-load lesson R16; 16 B records R18; bhist reuse R20;
//      R21: fused scan + rl8 sideband):
//      scan2 (cofs + bofs + Wpack, one kernel) ->
//      partA (LDS radix partition, deterministic, coalesced copy-out + rl8) ->
//      partB (per-bucket fine sort, histogram from 1 B rl8, L2-local; emits rowst).
//   3. row6_kernel (FUSED row pass + output GEMM): block = 16 rows; 4 waves x 4
//      rows; 8-slot scalar payload pipeline with 8 X-gathers in flight; (lr,-li)/
//      (li,lr) derived via s_xor/rot16; 6 dot2/edge; Y in LDS (400 B pitch);
//      MFMA per 16-col quadrant; NT-stores out + bias.

constexpr int N_NODES = 100000;
constexpr int E_EDGES = 1600000;
constexpr int CH = 64;
constexpr int NP = 100096;          // N padded to multiple of 256
constexpr int NBUCK = NP / 256;     // 391 coarse buckets (256 rows each)
constexpr int CHUNK_A = 2048;       // edges per partition block
constexpr int NBLK_A = (E_EDGES + CHUNK_A - 1) / CHUNK_A;   // 782
constexpr unsigned COLMASK = 0x1FFFFu;

typedef unsigned u32x4 __attribute__((ext_vector_type(4)));
typedef _Float16 h2f __attribute__((ext_vector_type(2)));
typedef _Float16 h8f __attribute__((ext_vector_type(8)));
typedef float f32x4 __attribute__((ext_vector_type(4)));

// f32 += dot(half2, half2) with f32 accumulation (v_dot2_f32_f16).
__device__ __forceinline__ float fdot2h(unsigned a, unsigned b, float c) {
#if __has_builtin(__builtin_amdgcn_fdot2)
    return __builtin_amdgcn_fdot2(__builtin_bit_cast(h2f, a),
                                  __builtin_bit_cast(h2f, b), c, false);
#else
    float2 af = __half22float2(__builtin_bit_cast(__half2, a));
    float2 bf = __half22float2(__builtin_bit_cast(__half2, b));
    return c + af.x * bf.x + af.y * bf.y;
#endif
}

__device__ __forceinline__ unsigned pack2(float a, float b) {
    return __builtin_bit_cast(unsigned, __floats2half2_rn(a, b));
}

__device__ __forceinline__ unsigned rot16(unsigned u) {
    return (u >> 16) | (u << 16);
}

__global__ __launch_bounds__(256) void init_out_kernel(const float* __restrict__ bias,
                                                       float* __restrict__ out) {
    int i = blockIdx.x * 256 + threadIdx.x;
    out[i] = bias[i & 63];
}

// ---------------- Phase 1: Xh pack + per-block histograms (bcnt pre-zeroed) ----------------
__global__ __launch_bounds__(1024) void prep_hist_kernel(const float* __restrict__ Xr,
                                                         const float* __restrict__ Xi,
                                                         const int* __restrict__ rows,
                                                         unsigned* __restrict__ Xh,
                                                         int* __restrict__ bcnt,
                                                         int* __restrict__ bhist) {
    __shared__ int lh[NBUCK];
    const int tid = threadIdx.x;
    for (int t = tid; t < NBUCK; t += 1024) lh[t] = 0;
    __syncthreads();
    const int base = blockIdx.x * CHUNK_A;          // grid = NBLK_A = 782
#pragma unroll
    for (int h = 0; h < 2; ++h) {
        const int i = base + h * 1024 + tid;
        if (i < E_EDGES) {                          // 1.6M float4 items == 1.6M edges
            const float4 r = ((const float4*)Xr)[i];
            const float4 m = ((const float4*)Xi)[i];
            uint4 u;
            u.x = pack2(r.x, m.x);
            u.y = pack2(r.y, m.y);
            u.z = pack2(r.z, m.z);
            u.w = pack2(r.w, m.w);
            ((uint4*)Xh)[i] = u;
            atomicAdd(&lh[rows[i] >> 8], 1);
        }
    }
    __syncthreads();
    for (int t = tid; t < NBUCK; t += 1024) {
        const int c = lh[t];
        bhist[(size_t)blockIdx.x * NBUCK + t] = c;   // save for scan2/partA
        if (c) atomicAdd(&bcnt[t], c);
    }
}

// ---------------- Fused scan: cofs[b] + bofs column-scan + Wpack (block 0) ----------------
__global__ __launch_bounds__(256) void scan2_kernel(const int* __restrict__ bcnt,
                                                    int* __restrict__ cofs,
                                                    const int* __restrict__ bhist,
                                                    int* __restrict__ bofs,
                                                    const float* __restrict__ W,
                                                    h8f* __restrict__ Bpack) {
    const int b = blockIdx.x;                 // grid = NBUCK
    const int t = threadIdx.x;
    __shared__ int s[256];
    __shared__ int carry;

    // cofs[b] = sum(bcnt[0..b-1]) — at most 391 ints, parallel reduce.
    int part = 0;
    for (int i = t; i < b; i += 256) part += bcnt[i];
    s[t] = part;
    __syncthreads();
    for (int off = 128; off > 0; off >>= 1) {
        if (t < off) s[t] += s[t + off];
        __syncthreads();
    }
    if (t == 0) {
        carry = s[0];
        cofs[b] = s[0];
        if (b == NBUCK - 1) cofs[NBUCK] = s[0] + bcnt[b];
    }
    __syncthreads();

    // Column scan of bhist[:, b] -> bofs[:, b].
    for (int base = 0; base < NBLK_A; base += 256) {
        const int idx = base + t;
        int v = (idx < NBLK_A) ? bhist[(size_t)idx * NBUCK + b] : 0;
        s[t] = v;
        __syncthreads();
        for (int off = 1; off < 256; off <<= 1) {
            int a = (t >= off) ? s[t - off] : 0;
            __syncthreads();
            s[t] += a;
            __syncthreads();
        }
        if (idx < NBLK_A) bofs[(size_t)idx * NBUCK + b] = carry + s[t] - v;
        __syncthreads();
        if (t == 255) carry += s[255];
        __syncthreads();
    }

    // W -> MFMA B-fragment pack (block 0 only; runs parallel with other blocks).
    if (b == 0) {
        for (int sidx = t; sidx < 24 * 64; sidx += 256) {
            const int L = sidx & 63;
            const int ntkc = sidx >> 6;
            const int nt = ntkc & 3;
            const int kc = ntkc >> 2;
            const int colb = nt * 16 + (L & 15);
            const int kbase = kc * 32 + ((L >> 4) << 3);
            h8f vv;
#pragma unroll
            for (int j = 0; j < 8; ++j) vv[j] = (_Float16)W[(kbase + j) * 64 + colb];
            Bpack[sidx] = vv;
        }
    }
}

// ---------------- Phase A: LDS radix partition (deterministic), coalesced copy-out ----------------
// record (16 B): {col | (row&255)<<17, h2(lr0,li0), h2(lr1,li1), h2(lr2,li2)}; rl8 sideband.
__global__ __launch_bounds__(1024) void partA_kernel(const int* __restrict__ rows,
                                                     const int* __restrict__ cols,
                                                     const float* __restrict__ Lr,
                                                     const float* __restrict__ Li,
                                                     const int* __restrict__ bhist,
                                                     const int* __restrict__ bofs,
                                                     u32x4* __restrict__ temp,
                                                     unsigned char* __restrict__ rl8) {
    __shared__ u32x4 sRec[CHUNK_A];       // 32,768 B, bucket-sorted records
    __shared__ int sDst[CHUNK_A];         //  8,192 B, global record index per record
    __shared__ int lh[NBUCK];
    __shared__ int lcur[NBUCK];
    __shared__ int gdel[NBUCK];           // global base - LDS base
    __shared__ int ss[512];
    const int tid = threadIdx.x;
    const int base = blockIdx.x * CHUNK_A;
    const int nedge = min(CHUNK_A, E_EDGES - base);

    if (tid < NBUCK) lh[tid] = bhist[(size_t)blockIdx.x * NBUCK + tid];
    __syncthreads();
    if (tid < 512) ss[tid] = (tid < NBUCK) ? lh[tid] : 0;
    __syncthreads();
    for (int off = 1; off < 512; off <<= 1) {
        int a = 0;
        if (tid < 512 && tid >= off) a = ss[tid - off];
        __syncthreads();
        if (tid < 512) ss[tid] += a;
        __syncthreads();
    }
    if (tid < NBUCK) {
        const int excl = ss[tid] - lh[tid];
        lcur[tid] = excl;
        gdel[tid] = bofs[(size_t)blockIdx.x * NBUCK + tid] - excl;
    }
    __syncthreads();

    for (int j = tid; j < nedge; j += 1024) {
        const int e = base + j;
        const int r = rows[e];
        const int bk = r >> 8;
        const int pos = atomicAdd(&lcur[bk], 1);
        u32x4 u;
        u.x = (unsigned)cols[e] | ((unsigned)(r & 255) << 17);
        u.y = pack2(Lr[e], Li[e]);
        u.z = pack2(Lr[E_EDGES + e], Li[E_EDGES + e]);
        u.w = pack2(Lr[2 * E_EDGES + e], Li[2 * E_EDGES + e]);
        sRec[pos] = u;
        sDst[pos] = gdel[bk] + pos;       // global record index
    }
    __syncthreads();

    // Coalesced copy-out: bucket-sorted LDS order -> piecewise-consecutive dests.
    for (int c = tid; c < nedge; c += 1024) {
        const u32x4 rec = sRec[c];
        const int d = sDst[c];
        temp[d] = rec;
        rl8[d] = (unsigned char)(rec.x >> 17);
    }
}

// ---------------- Phase B: per-bucket fine sort (L2-local), 1024 threads ----------------
__global__ __launch_bounds__(1024) void partB_kernel(const int* __restrict__ cofs,
                                                     const u32x4* __restrict__ temp,
                                                     const unsigned char* __restrict__ rl8,
                                                     u32x4* __restrict__ payload,
                                                     int* __restrict__ rowst) {
    const int b = blockIdx.x;                 // grid = NBUCK
    const int t = threadIdx.x;
    const int start = cofs[b];
    const int endp = cofs[b + 1];
    __shared__ int lh[256];
    __shared__ int s[256];
    if (t < 256) lh[t] = 0;
    __syncthreads();
    for (int i = start + t; i < endp; i += 1024)
        atomicAdd(&lh[rl8[i]], 1);            // 1 B/edge histogram pass
    __syncthreads();
    int v = 0;
    if (t < 256) {
        v = lh[t];
        s[t] = v;
    }
    __syncthreads();
    for (int off = 1; off < 256; off <<= 1) {
        int a = (t >= off && t < 256) ? s[t - off] : 0;
        __syncthreads();
        if (t < 256) s[t] += a;
        __syncthreads();
    }
    if (t < 256) {
        const int excl = s[t] - v;
        rowst[b * 256 + t] = start + excl;
        lh[t] = excl;                          // becomes per-row cursor
    }
    if (b == NBUCK - 1 && t == 0) rowst[NBUCK * 256] = endp;   // guard
    __syncthreads();
    for (int i = start + t; i < endp; i += 1024) {
        u32x4 q = temp[i];
        const int rl = (int)(q.x >> 17);
        const int pos = start + atomicAdd(&lh[rl], 1);   // random within ~66 KB -> L2
        payload[pos] = q;
    }
}

// ---------------- FUSED main pass: 16 rows/block; 8-deep pipeline + MFMA epilogue ----------------
__global__ __launch_bounds__(256) void row6_kernel(const int* __restrict__ rowst,
                                                   const u32x4* __restrict__ payload,
                                                   const unsigned* __restrict__ Xh,
                                                   const h8f* __restrict__ Bpack,
                                                   const float* __restrict__ bias,
                                                   float* __restrict__ out) {
    __shared__ __half sY[2][16][200];          // 400 B row pitch: 2-way LDS alias only
    const int w = (int)threadIdx.x >> 6;       // wave id = 4 rows / nt quadrant
    const int lane = threadIdx.x & 63;
    const int band = blockIdx.x * 16;          // grid = 6250 exact

    for (int q = 0; q < 4; ++q) {
        const int ri = w * 4 + q;
        const int r = __builtin_amdgcn_readfirstlane(band + ri);
        const int start = rowst[r];
        const int end = rowst[r + 1];
        const int n = end - start;

        float aR0 = 0.f, aI0 = 0.f, aR1 = 0.f, aI1 = 0.f, aR2 = 0.f, aI2 = 0.f;

        auto gx = [&](unsigned cw) -> unsigned {
            return Xh[(size_t)(cw & COLMASK) * 64 + lane];
        };
        auto accum = [&](const u32x4& qq, unsigned xv) {
            aR0 = fdot2h(qq.y ^ 0x80000000u, xv, aR0);
            aI0 = fdot2h(rot16(qq.y), xv, aI0);
            aR1 = fdot2h(qq.z ^ 0x80000000u, xv, aR1);
            aI1 = fdot2h(rot16(qq.z), xv, aI1);
            aR2 = fdot2h(qq.w ^ 0x80000000u, xv, aR2);
            aI2 = fdot2h(rot16(qq.w), xv, aI2);
        };

        if (n >= 12) {
            int p = start;
            u32x4 P0 = payload[p], P1 = payload[p + 1], P2 = payload[p + 2],
                  P3 = payload[p + 3], P4 = payload[p + 4], P5 = payload[p + 5],
                  P6 = payload[p + 6], P7 = payload[p + 7];
            unsigned x0 = gx(P0.x), x1 = gx(P1.x), x2 = gx(P2.x), x3 = gx(P3.x);
            unsigned x4 = gx(P4.x), x5 = gx(P5.x), x6 = gx(P6.x), x7 = gx(P7.x);

            for (; p + 11 < end; p += 4) {
                u32x4 Q0 = payload[p + 8], Q1 = payload[p + 9];
                u32x4 Q2 = payload[p + 10], Q3 = payload[p + 11];
                accum(P0, x0);
                accum(P1, x1);
                accum(P2, x2);
                accum(P3, x3);
                P0 = P4; P1 = P5; P2 = P6; P3 = P7;
                x0 = x4; x1 = x5; x2 = x6; x3 = x7;
                P4 = Q0; P5 = Q1; P6 = Q2; P7 = Q3;
                x4 = gx(P4.x);
                x5 = gx(P5.x);
                x6 = gx(P6.x);
                x7 = gx(P7.x);
            }
            accum(P0, x0);
            accum(P1, x1);
            accum(P2, x2);
            accum(P3, x3);
            accum(P4, x4);
            accum(P5, x5);
            accum(P6, x6);
            accum(P7, x7);
            for (p += 8; p < end; ++p) {
                u32x4 qq = payload[p];
                unsigned xv = gx(qq.x);
                accum(qq, xv);
            }
        } else {
            for (int p = start; p < end; ++p) {
                u32x4 qq = payload[p];
                unsigned xv = gx(qq.x);
                accum(qq, xv);
            }
        }

        sY[0][ri][lane] = __float2half(aR0);
        sY[0][ri][64 + lane] = __float2half(aR1);
        sY[0][ri][128 + lane] = __float2half(aR2);
        sY[1][ri][lane] = __float2half(aI0);
        sY[1][ri][64 + lane] = __float2half(aI1);
        sY[1][ri][128 + lane] = __float2half(aI2);
    }
    __syncthreads();

    // MFMA epilogue: wave w = column quadrant nt = w.
    const int nt = w;
    const int m = lane & 15;
    const int ko = (lane >> 4) << 3;
    f32x4 accR = (f32x4){0.f, 0.f, 0.f, 0.f};
    f32x4 accI = (f32x4){0.f, 0.f, 0.f, 0.f};
#pragma unroll
    for (int kc = 0; kc < 6; ++kc) {
        h8f bf = Bpack[(kc * 4 + nt) * 64 + lane];                    // L3-hot, 16 B/lane
        h8f aR = *(const h8f*)&sY[0][m][kc * 32 + ko];
        h8f aI = *(const h8f*)&sY[1][m][kc * 32 + ko];
        accR = __builtin_amdgcn_mfma_f32_16x16x32_f16(aR, bf, accR, 0, 0, 0);
        accI = __builtin_amdgcn_mfma_f32_16x16x32_f16(aI, bf, accI, 0, 0, 0);
    }
    const int colw = lane & 15;
    const int rbase = (lane >> 4) << 2;
    const float b = bias[nt * 16 + colw];
#pragma unroll
    for (int rr = 0; rr < 4; ++rr) {
        const int row = band + rbase + rr;
        __builtin_nontemporal_store(accR[rr] + b,
                                    &out[(size_t)row * 64 + nt * 16 + colw]);
        __builtin_nontemporal_store(accI[rr] + b,
                                    &out[(size_t)(N_NODES + row) * 64 + nt * 16 + colw]);
    }
}

// ================= Fallback kernels (small-ws paths) =================
template <int NK>
__global__ __launch_bounds__(256) void xw_kernel(const float* __restrict__ Xr,
                                                 const float* __restrict__ Xi,
                                                 const float* __restrict__ W,
                                                 __half2* __restrict__ XWh) {
    __shared__ float sW[NK][64][64];
    __shared__ float4 sX4[2][32][16];
    const int tid = threadIdx.x;

    float4* swf = (float4*)&sW[0][0][0];
    const float4* gW = (const float4*)W;
    for (int i = tid; i < NK * 1024; i += 256) swf[i] = gW[i];

    const int rowbase = blockIdx.x * 32;
    float4* sxf = (float4*)sX4;
    const float4* gXr = (const float4*)(Xr + (size_t)rowbase * CH);
    const float4* gXi = (const float4*)(Xi + (size_t)rowbase * CH);
    for (int i = tid; i < 512; i += 256) {
        sxf[i] = gXr[i];
        sxf[512 + i] = gXi[i];
    }
    __syncthreads();

    const int col = tid & 63;
    const int rg = tid >> 6;

    float acc[8][2 * NK];
#pragma unroll
    for (int i = 0; i < 8; ++i)
#pragma unroll
        for (int c2 = 0; c2 < 2 * NK; ++c2) acc[i][c2] = 0.0f;

#pragma unroll 2
    for (int j4 = 0; j4 < 16; ++j4) {
        float w[NK][4];
#pragma unroll
        for (int k = 0; k < NK; ++k)
#pragma unroll
            for (int jj = 0; jj < 4; ++jj) w[k][jj] = sW[k][j4 * 4 + jj][col];
#pragma unroll
        for (int i = 0; i < 8; ++i) {
            float4 xr = sX4[0][rg * 8 + i][j4];
            float4 xi = sX4[1][rg * 8 + i][j4];
            const float xra[4] = {xr.x, xr.y, xr.z, xr.w};
            const float xia[4] = {xi.x, xi.y, xi.z, xi.w};
#pragma unroll
            for (int jj = 0; jj < 4; ++jj)
#pragma unroll
                for (int k = 0; k < NK; ++k) {
                    acc[i][2 * k] += xra[jj] * w[k][jj];
                    acc[i][2 * k + 1] += xia[jj] * w[k][jj];
                }
        }
    }

#pragma unroll
    for (int i = 0; i < 8; ++i) {
        __half2* dst = XWh + (size_t)(rowbase + rg * 8 + i) * (NK * 64);
#pragma unroll
        for (int k = 0; k < NK; ++k)
            dst[k * 64 + col] = __floats2half2_rn(acc[i][2 * k], acc[i][2 * k + 1]);
    }
}

template <int NK>
__global__ __launch_bounds__(256) void edge_kernel(const int* __restrict__ rows,
                                                   const int* __restrict__ cols,
                                                   const float* __restrict__ Lr,
                                                   const float* __restrict__ Li,
                                                   const __half2* __restrict__ XWh,
                                                   float* __restrict__ out) {
    const int gid = blockIdx.x * 256 + threadIdx.x;
    const int e = gid >> 6;
    const int lane = gid & 63;
    if (e >= E_EDGES) return;

    const int row = rows[e];
    const int colN = cols[e];
    const __half2* xw = XWh + (size_t)colN * (NK * 64);

    float rc = 0.0f, ic = 0.0f;
#pragma unroll
    for (int k = 0; k < NK; ++k) {
        const float lr = Lr[(size_t)k * E_EDGES + e];
        const float li = Li[(size_t)k * E_EDGES + e];
        float2 v = __half22float2(xw[k * 64 + lane]);
        rc += lr * v.x - li * v.y;
        ic += li * v.x + lr * v.y;
    }
    unsafeAtomicAdd(out + (size_t)row * 64 + lane, rc);
    unsafeAtomicAdd(out + ((size_t)N_NODES + row) * 64 + lane, ic);
}

extern "C" void kernel_launch(void* const* d_in, const int* in_sizes, int n_in,
                              void* d_out, int out_size, void* d_ws, size_t ws_size,
                              hipStream_t stream) {
    const float* Xr = (const float*)d_in[0];
    const float* Xi = (const float*)d_in[1];
    const int* ei = (const int*)d_in[2];
    const float* Lr = (const float*)d_in[3];
    const float* Li = (const float*)d_in[4];
    const float* W = (const float*)d_in[5];
    const float* bias = (const float*)d_in[6];
    float* out = (float*)d_out;

    const int* rows = ei;
    const int* cols = ei + E_EDGES;

    char* wsb = (char*)d_ws;
    const int edge_grid = (int)((size_t)E_EDGES * 64 / 256);      // 400000
    const int gemm_grid = N_NODES / 32;                           // 3125

    // Main-path ws layout (16 B records + rl8 sideband)
    unsigned* Xh = (unsigned*)wsb;                                //  25,600,000 B
    unsigned* payload = (unsigned*)(wsb + 25600000);              //  25,600,000 B (16 B/edge)
    u32x4* temp = (u32x4*)(wsb + 51200000);                       //  25,600,000 B
    int* rowst = (int*)(wsb + 76800000);                          //     404,480 B (NP+1 used)
    int* bcnt = (int*)(wsb + 77204480);                           //       1,600 B
    int* cofs = (int*)(wsb + 77206080);                           //       1,600 B
    h8f* Bpack = (h8f*)(wsb + 77207680);                          //      24,576 B
    int* bhist = (int*)(wsb + 77232256);                          //   1,223,168 B
    int* bofs = (int*)(wsb + 78455424);                           //   1,223,168 B
    unsigned char* rl8 = (unsigned char*)(wsb + 79678592);        //   1,600,000 B
    const size_t need_new = 81278592;

    if (ws_size >= need_new) {
        hipMemsetAsync(bcnt, 0, NBUCK * sizeof(int), stream);
        prep_hist_kernel<<<NBLK_A, 1024, 0, stream>>>(Xr, Xi, rows, Xh, bcnt, bhist);
        scan2_kernel<<<NBUCK, 256, 0, stream>>>(bcnt, cofs, bhist, bofs, W, Bpack);
        partA_kernel<<<NBLK_A, 1024, 0, stream>>>(rows, cols, Lr, Li, bhist, bofs, temp,
                                                  rl8);
        partB_kernel<<<NBUCK, 1024, 0, stream>>>(cofs, temp, rl8, (u32x4*)payload, rowst);
        row6_kernel<<<N_NODES / 16, 256, 0, stream>>>(rowst, (const u32x4*)payload, Xh,
                                                      Bpack, bias, out);
        return;
    }

    // Fallback ws layout (atomic edge scatter over XWh table)
    __half2* XWh = (__half2*)wsb;                                 //  76,800,000 B
    const size_t need_onepass = 76800000;

    if (ws_size >= need_onepass) {
        init_out_kernel<<<2 * N_NODES * CH / 256, 256, 0, stream>>>(bias, out);
        xw_kernel<3><<<gemm_grid, 256, 0, stream>>>(Xr, Xi, W, XWh);
        edge_kernel<3><<<edge_grid, 256, 0, stream>>>(rows, cols, Lr, Li, XWh, out);
    } else {
        init_out_kernel<<<2 * N_NODES * CH / 256, 256, 0, stream>>>(bias, out);
        for (int k = 0; k < 3; ++k) {
            xw_kernel<1><<<gemm_grid, 256, 0, stream>>>(Xr, Xi, W + (size_t)k * 4096, XWh);
            edge_kernel<1><<<edge_grid, 256, 0, stream>>>(rows, cols,
                                                          Lr + (size_t)k * E_EDGES,
                                                          Li + (size_t)k * E_EDGES, XWh, out);
        }
    }
}